// Round 12
// baseline (1013.098 us; speedup 1.0000x reference)
//
#include <hip/hip_runtime.h>
#include <hip/hip_bf16.h>

// Problem constants (fixed by reference)
constexpr int GN = 100000;   // nodes
constexpr int GE = 1600000;  // edges
constexpr float FN = 100000.0f;
constexpr float BN_EPS = 1e-5f;

// Radix sort geometry: 2-pass LSD on dst (17 bits): low 8, then high 9.
constexpr int SB = 512;                   // sort blocks per pass
constexpr int TILE = (GE + SB - 1) / SB;  // 3125 edges per block (exact: 512*3125=GE)

typedef __attribute__((ext_vector_type(8))) short bf16x8;
typedef __attribute__((ext_vector_type(4))) float f32x4;

__device__ __forceinline__ unsigned packbf2(float a, float b) {
    __hip_bfloat162 h = __float22bfloat162_rn(float2{a, b});
    union { __hip_bfloat162 h2; unsigned u; } cv;
    cv.h2 = h;
    return cv.u;
}

__device__ __forceinline__ unsigned short bf16rn(float f) {
    unsigned u = __builtin_bit_cast(unsigned, f);
    unsigned r = (u + 0x7FFF + ((u >> 16) & 1)) >> 16;
    return (unsigned short)r;
}

__device__ __forceinline__ float bflo(unsigned u) {
    return __builtin_bit_cast(float, u << 16);
}
__device__ __forceinline__ float bfhi(unsigned u) {
    return __builtin_bit_cast(float, u & 0xFFFF0000u);
}
__device__ __forceinline__ float bfu16(unsigned short u) {
    return __builtin_bit_cast(float, (unsigned)u << 16);
}

// Bijective block permutation: adjacent chunk slots j, j+1 (same j>>6) map to
// blocks with equal b&7 == same XCD under round-robin dispatch, so adjacent
// output chunks are written XCD-locally (lines merge in that XCD's L2).
__device__ __forceinline__ int permb(int b) { return ((b & 7) << 6) | (b >> 3); }

// ---------------- radix sort of {eid, dst} by dst ----------------

// Pass-1 histogram (dst & 255) + folded weight bf16 conversion + stats zero.
__global__ __launch_bounds__(256) void h1_kernel(const int* __restrict__ dst,
                                                 int* __restrict__ hist1,
                                                 const float* __restrict__ l1w,
                                                 const float* __restrict__ l2w,
                                                 const float* __restrict__ c1w,
                                                 unsigned short* __restrict__ wb,
                                                 float* __restrict__ zeroBuf) {
    __shared__ int cnt[256];
    int b = blockIdx.x, t = threadIdx.x;
    if (b == 0 && t < 128) zeroBuf[t] = 0.f;
    cnt[t] = 0;
    __syncthreads();
    int e0 = b * TILE, e1 = min(e0 + TILE, GE);
    for (int i = e0 + t; i < e1; i += 256)
        atomicAdd(&cnt[dst[i] & 255], 1);
    __syncthreads();
    hist1[t * SB + permb(b)] = cnt[t];  // bin-major, XCD-grouped chunk order
    for (int i = b * 256 + t; i < 40960; i += SB * 256) {
        float v;
        if (i < 16384) v = l1w[i];
        else if (i < 32768) v = l2w[i - 16384];
        else v = c1w[i - 32768];
        wb[i] = bf16rn(v);
    }
}

// Within-bin exclusive prefix across the SB block-chunks; bin total out.
__global__ __launch_bounds__(256) void s1_kernel(int* __restrict__ hist,
                                                 int* __restrict__ binTot) {
    int bin = blockIdx.x, t = threadIdx.x;
    int v0 = hist[bin * SB + 2 * t], v1 = hist[bin * SB + 2 * t + 1];
    int s = v0 + v1;
    int lane = t & 63, w = t >> 6;
    int incl = s;
    for (int o = 1; o < 64; o <<= 1) {
        int u = __shfl_up(incl, o, 64);
        if (lane >= o) incl += u;
    }
    __shared__ int ws_[4];
    if (lane == 63) ws_[w] = incl;
    __syncthreads();
    int wb = 0;
#pragma unroll
    for (int k = 0; k < 4; ++k)
        if (k < w) wb += ws_[k];
    int ex = wb + incl - s;
    hist[bin * SB + 2 * t] = ex;
    hist[bin * SB + 2 * t + 1] = ex + v0;
    if (t == 255) binTot[bin] = ex + s;
}

// In-place exclusive scan of n<=512 bin totals (1 block).
__global__ __launch_bounds__(256) void s2_kernel(int* __restrict__ a, int n) {
    int t = threadIdx.x;
    int v0 = (2 * t < n) ? a[2 * t] : 0;
    int v1 = (2 * t + 1 < n) ? a[2 * t + 1] : 0;
    int s = v0 + v1;
    int lane = t & 63, w = t >> 6;
    int incl = s;
    for (int o = 1; o < 64; o <<= 1) {
        int u = __shfl_up(incl, o, 64);
        if (lane >= o) incl += u;
    }
    __shared__ int ws_[4];
    if (lane == 63) ws_[w] = incl;
    __syncthreads();
    int wb = 0;
#pragma unroll
    for (int k = 0; k < 4; ++k)
        if (k < w) wb += ws_[k];
    int ex = wb + incl - s;
    if (2 * t < n) a[2 * t] = ex;
    if (2 * t + 1 < n) a[2 * t + 1] = ex + v0;
}

// Pass-1 scatter (need not be stable): LDS cursors, no global atomics.
__global__ __launch_bounds__(256) void scat1_kernel(const int* __restrict__ dst,
                                                    const int* __restrict__ hist1,
                                                    const int* __restrict__ binBase1,
                                                    uint2* __restrict__ out) {
    __shared__ int base[256];
    int b = blockIdx.x, t = threadIdx.x;
    base[t] = hist1[t * SB + permb(b)] + binBase1[t];
    __syncthreads();
    int e0 = b * TILE, e1 = min(e0 + TILE, GE);
    for (int i = e0 + t; i < e1; i += 256) {
        int dv = dst[i];
        int pos = atomicAdd(&base[dv & 255], 1);  // LDS atomic only
        uint2 pr;
        pr.x = (unsigned)i;
        pr.y = (unsigned)dv;
        out[pos] = pr;
    }
}

// Pass-2 histogram (dst >> 8, 512 bins). Stability: block b processes input
// tile tp = permb(b) and writes counts at chunk slot tp, so chunk order in
// every bin == input tile order (stable) with XCD-local adjacent chunks.
__global__ __launch_bounds__(256) void h2_kernel(const uint2* __restrict__ in,
                                                 int* __restrict__ hist2) {
    __shared__ int cnt[512];
    int b = blockIdx.x, t = threadIdx.x;
    int tp = permb(b);
    cnt[t] = 0;
    cnt[t + 256] = 0;
    __syncthreads();
    int e0 = tp * TILE, e1 = min(e0 + TILE, GE);
    for (int i = e0 + t; i < e1; i += 256)
        atomicAdd(&cnt[in[i].y >> 8], 1);
    __syncthreads();
    hist2[t * SB + tp] = cnt[t];
    hist2[(t + 256) * SB + tp] = cnt[t + 256];
}

// Pass-2 scatter: stable (block b reads tile permb(b), writes chunk slot
// permb(b); within-block order preserved by wave-serialized sub-steps and
// in-wave ballot rank). No global atomics.
__global__ __launch_bounds__(256) void scat2_kernel(const uint2* __restrict__ in,
                                                    const int* __restrict__ hist2,
                                                    const int* __restrict__ binBase2,
                                                    uint2* __restrict__ out) {
    __shared__ int base[512];
    int b = blockIdx.x, t = threadIdx.x;
    int tp = permb(b);
    base[t] = hist2[t * SB + tp] + binBase2[t];
    base[t + 256] = hist2[(t + 256) * SB + tp] + binBase2[t + 256];
    __syncthreads();
    int e0 = tp * TILE, e1 = min(e0 + TILE, GE);
    int lane = t & 63, w = t >> 6;
    unsigned long long below = (1ull << lane) - 1ull;
    if (lane == 63) below = ~0ull >> 1;
    for (int r = e0; r < e1; r += 256) {
        int i = r + t;
        bool valid = (i < e1);
        uint2 el;
        el.x = 0u; el.y = 0u;
        if (valid) el = in[i];
        int bin = (int)(el.y >> 8);
        unsigned long long m = __ballot(valid);
#pragma unroll
        for (int bb = 0; bb < 9; ++bb) {
            unsigned long long bm = __ballot((bin >> bb) & 1);
            m &= ((bin >> bb) & 1) ? bm : ~bm;
        }
        int rank = __popcll(m & below);
        int cntm = __popcll(m);
        bool leader = valid && ((m & below) == 0ull);
#pragma unroll
        for (int ws = 0; ws < 4; ++ws) {
            if (w == ws && valid) {
                int p0 = base[bin];                 // all group lanes read (pre-write)
                if (leader) base[bin] = p0 + cntm;  // unique leader per bin
                out[p0 + rank] = el;
            }
            __syncthreads();
        }
    }
}

// CSR offsets by binary search in sorted dst (replaces hist+scan chain).
__global__ __launch_bounds__(256) void off_kernel(const uint2* __restrict__ sorted,
                                                  int* __restrict__ off) {
    int n = blockIdx.x * 256 + threadIdx.x;
    if (n > GN) return;
    if (n == GN) { off[GN] = GE; return; }
    int lo = 0, hi = GE;
    while (lo < hi) {
        int mid = (lo + hi) >> 1;
        if ((int)sorted[mid].y < n) lo = mid + 1; else hi = mid;
    }
    off[n] = lo;
}

// Final gather in sorted order: full-64B-line attr reads (quad-cooperative),
// purely sequential writes. Attr rows packed as bf16 (8 x bf16x2 = 32B).
__global__ __launch_bounds__(256) void gather_sorted_kernel(
    const uint2* __restrict__ sorted, const int* __restrict__ src,
    const float4* __restrict__ attr,
    int* __restrict__ srcS, uint2* __restrict__ attrS2) {
    int q = threadIdx.x & 3;                       // quarter of the row
    int row0 = blockIdx.x * 64 + (threadIdx.x >> 2);
    int stride = gridDim.x * 64;
    for (int p = row0; p < GE; p += stride) {
        int eid = (int)sorted[p].x;                // coalesced (4 lanes share line)
        float4 a = attr[(size_t)eid * 4 + q];      // 4 lanes cover one 64B line
        uint2 u;
        u.x = packbf2(a.x, a.y);
        u.y = packbf2(a.z, a.w);
        attrS2[(size_t)p * 4 + q] = u;             // sequential 8B/lane
        if (q == 0) srcS[p] = src[eid];            // sequential 4B, src via L3
    }
}

// ---------------- column stats on x (+ bf16 conversion of x) ----------------

__global__ __launch_bounds__(256) void col_stats64(const float* __restrict__ in,
                                                   float* __restrict__ sum,
                                                   float* __restrict__ sq,
                                                   unsigned short* __restrict__ outb) {
    int c = threadIdx.x & 63;
    int lr = threadIdx.x >> 6;
    float s = 0.f, q = 0.f;
    for (int r = blockIdx.x * 4 + lr; r < GN; r += gridDim.x * 4) {
        float v = in[(size_t)r * 64 + c];
        s += v;
        q += v * v;
        outb[(size_t)r * 64 + c] = bf16rn(v);
    }
    __shared__ float S[256];
    S[threadIdx.x] = s;
    __syncthreads();
    if (threadIdx.x < 64) {
        float a = S[threadIdx.x] + S[threadIdx.x + 64] + S[threadIdx.x + 128] + S[threadIdx.x + 192];
        atomicAdd(&sum[threadIdx.x], a);
    }
    __syncthreads();
    S[threadIdx.x] = q;
    __syncthreads();
    if (threadIdx.x < 64) {
        float a = S[threadIdx.x] + S[threadIdx.x + 64] + S[threadIdx.x + 128] + S[threadIdx.x + 192];
        atomicAdd(&sq[threadIdx.x], a);
    }
}

// ---------------- fused BN(pre) + GINE aggregation ----------------
// One wave per node (lane = feature). Uniform s_loads for src ids / attr rows
// (compiler-proven uniformity -- no explicit readfirstlane, r11 lesson);
// bf16 shift-decode + 16 fma per edge. Self term from the bf16 copy (hb).

template <int LEAKY>
__global__ __launch_bounds__(256) void aggregate_kernel(
    const unsigned short* __restrict__ hb,  // bf16 features (gather + self)
    const float* __restrict__ sumv, const float* __restrict__ sqv,
    const float* __restrict__ bnw, const float* __restrict__ bnb,
    const int* __restrict__ off,
    const int* __restrict__ srcS,
    const unsigned* __restrict__ attrS,     // bf16-packed rows, 8 uints (32B) each
    const float* __restrict__ Wle, const float* __restrict__ ble,
    const float* __restrict__ epsArr, int layer,
    unsigned short* __restrict__ zb,        // bf16 output (gemm1 input)
    float* __restrict__ zeroBuf) {
    if (blockIdx.x == 0 && threadIdx.x < 128) zeroBuf[threadIdx.x] = 0.f;
    const int d = threadIdx.x & 63;
    const int node = __builtin_amdgcn_readfirstlane(blockIdx.x * 4 + (threadIdx.x >> 6));

    float mean = sumv[d] / FN;
    float var = sqv[d] / FN - mean * mean;
    float cA = rsqrtf(var + BN_EPS) * bnw[d];
    float cB = bnb[d] - mean * cA;

    float wq[16];
#pragma unroll
    for (int k = 0; k < 16; k += 4) {
        float4 t = *(const float4*)(Wle + d * 16 + k);
        wq[k] = t.x; wq[k + 1] = t.y; wq[k + 2] = t.z; wq[k + 3] = t.w;
    }
    float be = ble[d];
    float epsv = 1.0f + epsArr[layer];

    int p0 = off[node], p1 = off[node + 1];  // uniform -> s_load
    float hv = bfu16(hb[(((unsigned)node) << 6) + d]); // self term (bf16, L2)

    float acc = 0.0f;
    int p = p0;
    int pfull = p0 + ((p1 - p0) & ~7);
    for (; p < pfull; p += 8) {              // full groups: no masking
        int idx[8];
#pragma unroll
        for (int j = 0; j < 8; ++j) idx[j] = srcS[p + j];  // s_load (contiguous)
        float g[8];
#pragma unroll
        for (int j = 0; j < 8; ++j)
            g[j] = bfu16(hb[(((unsigned)idx[j]) << 6) + d]);  // 32-bit offset gathers
#pragma unroll
        for (int j = 0; j < 8; ++j) {
            const uint4* ar = (const uint4*)(attrS + (size_t)(p + j) * 8);
            uint4 A = ar[0], B = ar[1];      // uniform -> s_load / broadcast
            float e = be;
            e = fmaf(bflo(A.x), wq[0], e);  e = fmaf(bfhi(A.x), wq[1], e);
            e = fmaf(bflo(A.y), wq[2], e);  e = fmaf(bfhi(A.y), wq[3], e);
            e = fmaf(bflo(A.z), wq[4], e);  e = fmaf(bfhi(A.z), wq[5], e);
            e = fmaf(bflo(A.w), wq[6], e);  e = fmaf(bfhi(A.w), wq[7], e);
            e = fmaf(bflo(B.x), wq[8], e);  e = fmaf(bfhi(B.x), wq[9], e);
            e = fmaf(bflo(B.y), wq[10], e); e = fmaf(bfhi(B.y), wq[11], e);
            e = fmaf(bflo(B.z), wq[12], e); e = fmaf(bfhi(B.z), wq[13], e);
            e = fmaf(bflo(B.w), wq[14], e); e = fmaf(bfhi(B.w), wq[15], e);
            float gg = g[j] * cA + cB;
            if (LEAKY) gg = fmaxf(gg, 0.01f * gg);
            acc += fmaxf(gg + e, 0.f);
        }
    }
    for (; p < p1; p += 4) {                 // masked tail, groups of 4
        int idx[4];
#pragma unroll
        for (int j = 0; j < 4; ++j) {
            int q = p + j;
            if (q > p1 - 1) q = p1 - 1;
            idx[j] = srcS[q];
        }
        float g[4];
#pragma unroll
        for (int j = 0; j < 4; ++j)
            g[j] = bfu16(hb[(((unsigned)idx[j]) << 6) + d]);
#pragma unroll
        for (int j = 0; j < 4; ++j) {
            int q = p + j;
            if (q > p1 - 1) q = p1 - 1;
            const uint4* ar = (const uint4*)(attrS + (size_t)q * 8);
            uint4 A = ar[0], B = ar[1];
            float e = be;
            e = fmaf(bflo(A.x), wq[0], e);  e = fmaf(bfhi(A.x), wq[1], e);
            e = fmaf(bflo(A.y), wq[2], e);  e = fmaf(bfhi(A.y), wq[3], e);
            e = fmaf(bflo(A.z), wq[4], e);  e = fmaf(bfhi(A.z), wq[5], e);
            e = fmaf(bflo(A.w), wq[6], e);  e = fmaf(bfhi(A.w), wq[7], e);
            e = fmaf(bflo(B.x), wq[8], e);  e = fmaf(bfhi(B.x), wq[9], e);
            e = fmaf(bflo(B.y), wq[10], e); e = fmaf(bfhi(B.y), wq[11], e);
            e = fmaf(bflo(B.z), wq[12], e); e = fmaf(bfhi(B.z), wq[13], e);
            e = fmaf(bflo(B.w), wq[14], e); e = fmaf(bfhi(B.w), wq[15], e);
            float gg = g[j] * cA + cB;
            if (LEAKY) gg = fmaxf(gg, 0.01f * gg);
            float m = fmaxf(gg + e, 0.f);
            acc += (p + j < p1) ? m : 0.f;
        }
    }
    hv = hv * cA + cB;
    if (LEAKY) hv = fmaxf(hv, 0.01f * hv);
    zb[(size_t)node * 64 + d] = bf16rn(epsv * hv + acc);
}

// ---------------- MFMA bf16 GEMM: dst = f(src) @ W^T + bias [+resid] ----------------
// Block = 256 thr = 4 waves; tile 64 rows x 64 cols; grid-stride over row tiles.
// BN_IN+ABF16: bf16 input decoded + BN + leaky + repack (z stored as bf16).

template <bool BN_IN, bool ABF16, bool STATS, bool RESID, bool BF16OUT, bool F32OUT>
__global__ __launch_bounds__(256) void gemm_mfma(
    const float* __restrict__ srcf, const unsigned short* __restrict__ srcb, int src_ld,
    const unsigned short* __restrict__ Wb,   // bf16 [ncols][64]
    const float* __restrict__ bias,
    float* __restrict__ dst, int dst_ld,
    unsigned short* __restrict__ dstb, int dstb_ld,
    const float* __restrict__ resid,
    const float* __restrict__ statsInSum, const float* __restrict__ statsInSq,
    const float* __restrict__ bnw, const float* __restrict__ bnb,
    float* __restrict__ statsOutSum, float* __restrict__ statsOutSq,
    float* __restrict__ zeroBuf, int zeroN) {
    __shared__ float cA[64], cB[64];
    __shared__ float sS[64], sQ[64];
    int tid = threadIdx.x;
    if (zeroBuf && blockIdx.x == 0 && blockIdx.y == 0 && tid < zeroN) zeroBuf[tid] = 0.f;
    int c0 = blockIdx.y * 64;

    if (BN_IN) {
        if (tid < 64) {
            float m = statsInSum[tid] / FN;
            float v = statsInSq[tid] / FN - m * m;
            float a = rsqrtf(v + BN_EPS) * bnw[tid];
            cA[tid] = a;
            cB[tid] = bnb[tid] - m * a;
        }
        __syncthreads();
    }

    int w = tid >> 6, lane = tid & 63;
    int n16 = lane & 15, quad = lane >> 4;

    // B fragments once per block
    bf16x8 bfr[4][2];
#pragma unroll
    for (int t = 0; t < 4; ++t) {
        int col = c0 + t * 16 + n16;
        const unsigned short* bsrc = Wb + (size_t)col * 64 + quad * 8;
#pragma unroll
        for (int kk = 0; kk < 2; ++kk)
            bfr[t][kk] = *(const bf16x8*)(bsrc + kk * 32);
    }

    float ls[4] = {0.f, 0.f, 0.f, 0.f}, lq[4] = {0.f, 0.f, 0.f, 0.f};
    constexpr int NT = (GN + 63) / 64;  // 1563
    for (int tile = blockIdx.x; tile < NT; tile += gridDim.x) {
        int r0 = tile * 64;
        int arow = r0 + w * 16 + n16;
        int arc = arow < GN ? arow : 0;

        bf16x8 afr[2];
        if (ABF16 && !BN_IN) {
            const unsigned short* asrc = srcb + (size_t)arc * src_ld + quad * 8;
#pragma unroll
            for (int kk = 0; kk < 2; ++kk)
                afr[kk] = *(const bf16x8*)(asrc + kk * 32);
        } else if (ABF16 && BN_IN) {
            const unsigned short* asrc = srcb + (size_t)arc * src_ld + quad * 8;
#pragma unroll
            for (int kk = 0; kk < 2; ++kk) {
                uint4 rw = *(const uint4*)(asrc + kk * 32);
                float av[8] = {bflo(rw.x), bfhi(rw.x), bflo(rw.y), bfhi(rw.y),
                               bflo(rw.z), bfhi(rw.z), bflo(rw.w), bfhi(rw.w)};
                int kb = quad * 8 + kk * 32;
#pragma unroll
                for (int j = 0; j < 8; ++j) {
                    float t = av[j] * cA[kb + j] + cB[kb + j];
                    av[j] = fmaxf(t, 0.01f * t);
                }
                uint4 fu;
                fu.x = packbf2(av[0], av[1]); fu.y = packbf2(av[2], av[3]);
                fu.z = packbf2(av[4], av[5]); fu.w = packbf2(av[6], av[7]);
                afr[kk] = __builtin_bit_cast(bf16x8, fu);
            }
        } else {
            const float* asrc = srcf + (size_t)arc * src_ld + quad * 8;
#pragma unroll
            for (int kk = 0; kk < 2; ++kk) {
                const float4* p = (const float4*)(asrc + kk * 32);
                float4 x0 = p[0], x1 = p[1];
                float av[8] = {x0.x, x0.y, x0.z, x0.w, x1.x, x1.y, x1.z, x1.w};
                if (BN_IN) {
                    int kb = quad * 8 + kk * 32;
#pragma unroll
                    for (int j = 0; j < 8; ++j) {
                        float t = av[j] * cA[kb + j] + cB[kb + j];
                        av[j] = fmaxf(t, 0.01f * t);
                    }
                }
                uint4 fu;
                fu.x = packbf2(av[0], av[1]); fu.y = packbf2(av[2], av[3]);
                fu.z = packbf2(av[4], av[5]); fu.w = packbf2(av[6], av[7]);
                afr[kk] = __builtin_bit_cast(bf16x8, fu);
            }
        }

        f32x4 acc[4] = {{0.f, 0.f, 0.f, 0.f}, {0.f, 0.f, 0.f, 0.f},
                        {0.f, 0.f, 0.f, 0.f}, {0.f, 0.f, 0.f, 0.f}};
#pragma unroll
        for (int t = 0; t < 4; ++t) {
            acc[t] = __builtin_amdgcn_mfma_f32_16x16x32_bf16(afr[0], bfr[t][0], acc[t], 0, 0, 0);
            acc[t] = __builtin_amdgcn_mfma_f32_16x16x32_bf16(afr[1], bfr[t][1], acc[t], 0, 0, 0);
        }

        // epilogue: D row = r0 + w*16 + quad*4 + r, col = c0 + t*16 + n16
#pragma unroll
        for (int t = 0; t < 4; ++t) {
            int col = c0 + t * 16 + n16;
            float bv = bias[col];
#pragma unroll
            for (int r = 0; r < 4; ++r) {
                int row = r0 + w * 16 + quad * 4 + r;
                if (row < GN) {
                    float o = acc[t][r] + bv;
                    if (RESID) o += resid[(size_t)row * dst_ld + col];
                    if (F32OUT) dst[(size_t)row * dst_ld + col] = o;
                    if (BF16OUT) dstb[(size_t)row * dstb_ld + col] = bf16rn(o);
                    if (STATS) {
                        float oS = o;
                        if (BF16OUT && !F32OUT) oS = bfu16(bf16rn(o));  // stats match stored data
                        ls[t] += oS;
                        lq[t] += oS * oS;
                    }
                }
            }
        }
    }

    if (STATS) {
        if (tid < 64) { sS[tid] = 0.f; sQ[tid] = 0.f; }
        __syncthreads();
#pragma unroll
        for (int t = 0; t < 4; ++t) {
            float s = ls[t], q = lq[t];
            s += __shfl_down(s, 16, 64); s += __shfl_down(s, 32, 64);
            q += __shfl_down(q, 16, 64); q += __shfl_down(q, 32, 64);
            if (lane < 16) {
                atomicAdd(&sS[t * 16 + n16], s);
                atomicAdd(&sQ[t * 16 + n16], q);
            }
        }
        __syncthreads();
        if (tid < 64) {
            atomicAdd(&statsOutSum[c0 + tid], sS[tid]);
            atomicAdd(&statsOutSq[c0 + tid], sQ[tid]);
        }
    }
}

// ---------------- classifier tail (bf16 y1) ----------------

__global__ __launch_bounds__(256) void cls2_kernel(
    const unsigned short* __restrict__ y1b,
    const float* __restrict__ sum, const float* __restrict__ sq,
    const float* __restrict__ bnw, const float* __restrict__ bnb,
    const float* __restrict__ w2, const float* __restrict__ b2,
    float* __restrict__ out) {
    int node = blockIdx.x * 4 + (threadIdx.x >> 6);
    int d = threadIdx.x & 63;
    if (node >= GN) return;
    float partial = 0.f;
#pragma unroll
    for (int hh = 0; hh < 2; ++hh) {
        int c = d + hh * 64;
        float m = sum[c] / FN;
        float var = sq[c] / FN - m * m;
        float a = rsqrtf(var + BN_EPS) * bnw[c];
        float v = bfu16(y1b[(size_t)node * 128 + c]);
        v = v * a + (bnb[c] - m * a);
        v = fmaxf(v, 0.01f * v);
        partial += v * w2[c];
    }
    for (int o = 32; o >= 1; o >>= 1) partial += __shfl_down(partial, o, 64);
    if (d == 0) out[node] = partial + b2[0];
}

// ---------------- launcher ----------------

extern "C" void kernel_launch(void* const* d_in, const int* in_sizes, int n_in,
                              void* d_out, int out_size, void* d_ws, size_t ws_size,
                              hipStream_t stream) {
    (void)in_sizes; (void)n_in; (void)out_size; (void)ws_size;
    const float* x    = (const float*)d_in[0];
    const int*   ei   = (const int*)d_in[1];
    const float* attr = (const float*)d_in[2];
    const float* bnpw = (const float*)d_in[3];
    const float* bnpb = (const float*)d_in[4];
    const float* elw  = (const float*)d_in[5];
    const float* elb  = (const float*)d_in[6];
    const float* l1w  = (const float*)d_in[7];
    const float* l1b  = (const float*)d_in[8];
    const float* bnmw = (const float*)d_in[9];
    const float* bnmb = (const float*)d_in[10];
    const float* l2w  = (const float*)d_in[11];
    const float* l2b  = (const float*)d_in[12];
    const float* epsA = (const float*)d_in[13];
    const float* c1w  = (const float*)d_in[14];
    const float* c1b  = (const float*)d_in[15];
    const float* cbw  = (const float*)d_in[16];
    const float* cbb  = (const float*)d_in[17];
    const float* c2w  = (const float*)d_in[18];
    const float* c2b  = (const float*)d_in[19];
    const int* srcArr = ei;
    const int* dstArr = ei + GE;

    char* base = (char*)d_ws;
    size_t ofs = 0;
    auto alloc = [&](size_t bytes) {
        void* p = base + ofs;
        ofs = (ofs + bytes + 1023) & ~(size_t)1023;
        return p;
    };
    int* off              = (int*)alloc((size_t)(GN + 1) * 4);
    int* hist1            = (int*)alloc((size_t)256 * SB * 4);
    int* hist2            = (int*)alloc((size_t)512 * SB * 4);
    int* binTot1          = (int*)alloc(512 * 4);
    int* binTot2          = (int*)alloc(512 * 4);
    int* src_sorted       = (int*)alloc((size_t)GE * 4);
    unsigned* attr_sorted = (unsigned*)alloc((size_t)GE * 32);  // bf16 rows, 32B
    unsigned short* wbf   = (unsigned short*)alloc(40960 * 2);
    float* stP0 = (float*)alloc(512);
    float* stP1 = (float*)alloc(512);
    float* stM  = (float*)alloc(512);
    float* stC  = (float*)alloc(1024);
    float* h = (float*)alloc((size_t)GN * 256);
    float* z = (float*)alloc((size_t)GN * 256);   // only aliased by sort pairs now
    unsigned short* zb  = (unsigned short*)alloc((size_t)GN * 128);
    unsigned short* zb2 = (unsigned short*)alloc((size_t)GN * 128);
    unsigned short* xb  = (unsigned short*)alloc((size_t)GN * 128);
    unsigned short* hb  = (unsigned short*)alloc((size_t)GN * 128);
    unsigned short* y1b = (unsigned short*)attr_sorted;  // reuse (25.6MB <= 51.2MB)
    // Radix ping-pong pairs alias z (25.6MB = 2 x GE*8B); z is otherwise unused.
    uint2* pairsA = (uint2*)z;
    uint2* pairsB = (uint2*)((char*)z + (size_t)GE * 8);

    float* stP[2] = {stP0, stP1};

    // ---- deterministic 2-pass radix sort by dst (no global atomics) ----
    h1_kernel<<<SB, 256, 0, stream>>>(dstArr, hist1, l1w, l2w, c1w, wbf, stP0);
    s1_kernel<<<256, 256, 0, stream>>>(hist1, binTot1);
    s2_kernel<<<1, 256, 0, stream>>>(binTot1, 256);
    scat1_kernel<<<SB, 256, 0, stream>>>(dstArr, hist1, binTot1, pairsA);
    h2_kernel<<<SB, 256, 0, stream>>>(pairsA, hist2);
    s1_kernel<<<512, 256, 0, stream>>>(hist2, binTot2);
    s2_kernel<<<1, 256, 0, stream>>>(binTot2, 512);
    scat2_kernel<<<SB, 256, 0, stream>>>(pairsA, hist2, binTot2, pairsB);
    off_kernel<<<392, 256, 0, stream>>>(pairsB, off);
    gather_sorted_kernel<<<4096, 256, 0, stream>>>(pairsB, srcArr, (const float4*)attr,
                                                   src_sorted, (uint2*)attr_sorted);

    // ---- layer-0 pre-BN stats on x (+ x -> bf16) ----
    col_stats64<<<512, 256, 0, stream>>>(x, stP0, stP0 + 64, xb);

    const unsigned short* hbsrc = xb;
    for (int i = 0; i < 4; ++i) {
        float* sIn = stP[i & 1];
        float* sNext = stP[(i + 1) & 1];
        if (i == 0)
            aggregate_kernel<0><<<25000, 256, 0, stream>>>(
                hbsrc, sIn, sIn + 64, bnpw + i * 64, bnpb + i * 64,
                off, src_sorted, attr_sorted, elw + i * 1024, elb + i * 64, epsA, i,
                zb, stM);
        else
            aggregate_kernel<1><<<25000, 256, 0, stream>>>(
                hbsrc, sIn, sIn + 64, bnpw + i * 64, bnpb + i * 64,
                off, src_sorted, attr_sorted, elw + i * 1024, elb + i * 64, epsA, i,
                zb, stM);
        // gemm1: zb2(bf16) = zb @ l1w^T + b ; stats (on rounded) -> stM
        gemm_mfma<false, true, true, false, true, false><<<dim3(782, 1), 256, 0, stream>>>(
            nullptr, zb, 64, wbf + i * 4096, l1b + i * 64, nullptr, 0, zb2, 64, nullptr,
            nullptr, nullptr, nullptr, nullptr, stM, stM + 64,
            (i == 3) ? stC : sNext, (i == 3) ? 256 : 128);
        // gemm2: h = leaky(bn(zb2)) @ l2w^T + b [+h] ; stats -> sNext ; bf16 copy
        if (i == 0)
            gemm_mfma<true, true, true, false, true, true><<<dim3(782, 1), 256, 0, stream>>>(
                nullptr, zb2, 64, wbf + 16384 + i * 4096, l2b + i * 64, h, 64, hb, 64,
                nullptr, stM, stM + 64, bnmw + i * 64, bnmb + i * 64,
                sNext, sNext + 64, nullptr, 0);
        else if (i < 3)
            gemm_mfma<true, true, true, true, true, true><<<dim3(782, 1), 256, 0, stream>>>(
                nullptr, zb2, 64, wbf + 16384 + i * 4096, l2b + i * 64, h, 64, hb, 64,
                h, stM, stM + 64, bnmw + i * 64, bnmb + i * 64,
                sNext, sNext + 64, nullptr, 0);
        else
            gemm_mfma<true, true, false, true, true, true><<<dim3(782, 1), 256, 0, stream>>>(
                nullptr, zb2, 64, wbf + 16384 + i * 4096, l2b + i * 64, h, 64, hb, 64,
                h, stM, stM + 64, bnmw + i * 64, bnmb + i * 64,
                nullptr, nullptr, nullptr, 0);
        hbsrc = hb;
    }

    // ---- classifier: y1b = hb @ c1w^T + b (bf16 out only), then BN+leaky+dot ----
    dim3 gc(391, 2);
    gemm_mfma<false, true, true, false, true, false><<<gc, 256, 0, stream>>>(
        nullptr, hb, 64, wbf + 32768, c1b, nullptr, 128, y1b, 128, nullptr,
        nullptr, nullptr, nullptr, nullptr, stC, stC + 128, nullptr, 0);
    cls2_kernel<<<25000, 256, 0, stream>>>(y1b, stC, stC + 128, cbw, cbb, c2w, c2b,
                                           (float*)d_out);
}

// Round 13
// 1008.334 us; speedup vs baseline: 1.0047x; 1.0047x over previous
//
#include <hip/hip_runtime.h>
#include <hip/hip_bf16.h>

// Problem constants (fixed by reference)
constexpr int GN = 100000;   // nodes
constexpr int GE = 1600000;  // edges
constexpr float FN = 100000.0f;
constexpr float BN_EPS = 1e-5f;

// Radix sort geometry: 2-pass LSD on dst (17 bits): low 8, then high 9.
constexpr int SB = 512;                   // sort blocks per pass
constexpr int TILE = (GE + SB - 1) / SB;  // 3125 edges per block (exact: 512*3125=GE)

typedef __attribute__((ext_vector_type(8))) short bf16x8;
typedef __attribute__((ext_vector_type(4))) float f32x4;

__device__ __forceinline__ unsigned packbf2(float a, float b) {
    __hip_bfloat162 h = __float22bfloat162_rn(float2{a, b});
    union { __hip_bfloat162 h2; unsigned u; } cv;
    cv.h2 = h;
    return cv.u;
}

__device__ __forceinline__ unsigned short bf16rn(float f) {
    unsigned u = __builtin_bit_cast(unsigned, f);
    unsigned r = (u + 0x7FFF + ((u >> 16) & 1)) >> 16;
    return (unsigned short)r;
}

__device__ __forceinline__ float bflo(unsigned u) {
    return __builtin_bit_cast(float, u << 16);
}
__device__ __forceinline__ float bfhi(unsigned u) {
    return __builtin_bit_cast(float, u & 0xFFFF0000u);
}
__device__ __forceinline__ float bfu16(unsigned short u) {
    return __builtin_bit_cast(float, (unsigned)u << 16);
}

// Bijective block permutation: adjacent chunk slots j, j+1 (same j>>6) map to
// blocks with equal b&7 == same XCD under round-robin dispatch, so adjacent
// output chunks are written XCD-locally (lines merge in that XCD's L2).
__device__ __forceinline__ int permb(int b) { return ((b & 7) << 6) | (b >> 3); }

// ---------------- radix sort of {eid, dst} by dst ----------------

// Pass-1 histogram (dst & 255) + folded weight bf16 conversion + stats zero.
__global__ __launch_bounds__(256) void h1_kernel(const int* __restrict__ dst,
                                                 int* __restrict__ hist1,
                                                 const float* __restrict__ l1w,
                                                 const float* __restrict__ l2w,
                                                 const float* __restrict__ c1w,
                                                 unsigned short* __restrict__ wb,
                                                 float* __restrict__ zeroBuf) {
    __shared__ int cnt[256];
    int b = blockIdx.x, t = threadIdx.x;
    if (b == 0 && t < 128) zeroBuf[t] = 0.f;
    cnt[t] = 0;
    __syncthreads();
    int e0 = b * TILE, e1 = min(e0 + TILE, GE);
    for (int i = e0 + t; i < e1; i += 256)
        atomicAdd(&cnt[dst[i] & 255], 1);
    __syncthreads();
    hist1[t * SB + permb(b)] = cnt[t];  // bin-major, XCD-grouped chunk order
    for (int i = b * 256 + t; i < 40960; i += SB * 256) {
        float v;
        if (i < 16384) v = l1w[i];
        else if (i < 32768) v = l2w[i - 16384];
        else v = c1w[i - 32768];
        wb[i] = bf16rn(v);
    }
}

// Within-bin exclusive prefix across the SB block-chunks; bin total out.
__global__ __launch_bounds__(256) void s1_kernel(int* __restrict__ hist,
                                                 int* __restrict__ binTot) {
    int bin = blockIdx.x, t = threadIdx.x;
    int v0 = hist[bin * SB + 2 * t], v1 = hist[bin * SB + 2 * t + 1];
    int s = v0 + v1;
    int lane = t & 63, w = t >> 6;
    int incl = s;
    for (int o = 1; o < 64; o <<= 1) {
        int u = __shfl_up(incl, o, 64);
        if (lane >= o) incl += u;
    }
    __shared__ int ws_[4];
    if (lane == 63) ws_[w] = incl;
    __syncthreads();
    int wb = 0;
#pragma unroll
    for (int k = 0; k < 4; ++k)
        if (k < w) wb += ws_[k];
    int ex = wb + incl - s;
    hist[bin * SB + 2 * t] = ex;
    hist[bin * SB + 2 * t + 1] = ex + v0;
    if (t == 255) binTot[bin] = ex + s;
}

// In-place exclusive scan of n<=512 bin totals (1 block).
__global__ __launch_bounds__(256) void s2_kernel(int* __restrict__ a, int n) {
    int t = threadIdx.x;
    int v0 = (2 * t < n) ? a[2 * t] : 0;
    int v1 = (2 * t + 1 < n) ? a[2 * t + 1] : 0;
    int s = v0 + v1;
    int lane = t & 63, w = t >> 6;
    int incl = s;
    for (int o = 1; o < 64; o <<= 1) {
        int u = __shfl_up(incl, o, 64);
        if (lane >= o) incl += u;
    }
    __shared__ int ws_[4];
    if (lane == 63) ws_[w] = incl;
    __syncthreads();
    int wb = 0;
#pragma unroll
    for (int k = 0; k < 4; ++k)
        if (k < w) wb += ws_[k];
    int ex = wb + incl - s;
    if (2 * t < n) a[2 * t] = ex;
    if (2 * t + 1 < n) a[2 * t + 1] = ex + v0;
}

// Pass-1 scatter (need not be stable): LDS cursors, no global atomics.
__global__ __launch_bounds__(256) void scat1_kernel(const int* __restrict__ dst,
                                                    const int* __restrict__ hist1,
                                                    const int* __restrict__ binBase1,
                                                    uint2* __restrict__ out) {
    __shared__ int base[256];
    int b = blockIdx.x, t = threadIdx.x;
    base[t] = hist1[t * SB + permb(b)] + binBase1[t];
    __syncthreads();
    int e0 = b * TILE, e1 = min(e0 + TILE, GE);
    for (int i = e0 + t; i < e1; i += 256) {
        int dv = dst[i];
        int pos = atomicAdd(&base[dv & 255], 1);  // LDS atomic only
        uint2 pr;
        pr.x = (unsigned)i;
        pr.y = (unsigned)dv;
        out[pos] = pr;
    }
}

// Pass-2 histogram (dst >> 8, 512 bins). Stability: block b processes input
// tile tp = permb(b) and writes counts at chunk slot tp, so chunk order in
// every bin == input tile order (stable) with XCD-local adjacent chunks.
__global__ __launch_bounds__(256) void h2_kernel(const uint2* __restrict__ in,
                                                 int* __restrict__ hist2) {
    __shared__ int cnt[512];
    int b = blockIdx.x, t = threadIdx.x;
    int tp = permb(b);
    cnt[t] = 0;
    cnt[t + 256] = 0;
    __syncthreads();
    int e0 = tp * TILE, e1 = min(e0 + TILE, GE);
    for (int i = e0 + t; i < e1; i += 256)
        atomicAdd(&cnt[in[i].y >> 8], 1);
    __syncthreads();
    hist2[t * SB + tp] = cnt[t];
    hist2[(t + 256) * SB + tp] = cnt[t + 256];
}

// Pass-2 scatter: stable (block b reads tile permb(b), writes chunk slot
// permb(b); within-block order preserved by wave-serialized sub-steps and
// in-wave ballot rank). No global atomics.
__global__ __launch_bounds__(256) void scat2_kernel(const uint2* __restrict__ in,
                                                    const int* __restrict__ hist2,
                                                    const int* __restrict__ binBase2,
                                                    uint2* __restrict__ out) {
    __shared__ int base[512];
    int b = blockIdx.x, t = threadIdx.x;
    int tp = permb(b);
    base[t] = hist2[t * SB + tp] + binBase2[t];
    base[t + 256] = hist2[(t + 256) * SB + tp] + binBase2[t + 256];
    __syncthreads();
    int e0 = tp * TILE, e1 = min(e0 + TILE, GE);
    int lane = t & 63, w = t >> 6;
    unsigned long long below = (1ull << lane) - 1ull;
    if (lane == 63) below = ~0ull >> 1;
    for (int r = e0; r < e1; r += 256) {
        int i = r + t;
        bool valid = (i < e1);
        uint2 el;
        el.x = 0u; el.y = 0u;
        if (valid) el = in[i];
        int bin = (int)(el.y >> 8);
        unsigned long long m = __ballot(valid);
#pragma unroll
        for (int bb = 0; bb < 9; ++bb) {
            unsigned long long bm = __ballot((bin >> bb) & 1);
            m &= ((bin >> bb) & 1) ? bm : ~bm;
        }
        int rank = __popcll(m & below);
        int cntm = __popcll(m);
        bool leader = valid && ((m & below) == 0ull);
#pragma unroll
        for (int ws = 0; ws < 4; ++ws) {
            if (w == ws && valid) {
                int p0 = base[bin];                 // all group lanes read (pre-write)
                if (leader) base[bin] = p0 + cntm;  // unique leader per bin
                out[p0 + rank] = el;
            }
            __syncthreads();
        }
    }
}

// CSR offsets by binary search in sorted dst (replaces hist+scan chain).
__global__ __launch_bounds__(256) void off_kernel(const uint2* __restrict__ sorted,
                                                  int* __restrict__ off) {
    int n = blockIdx.x * 256 + threadIdx.x;
    if (n > GN) return;
    if (n == GN) { off[GN] = GE; return; }
    int lo = 0, hi = GE;
    while (lo < hi) {
        int mid = (lo + hi) >> 1;
        if ((int)sorted[mid].y < n) lo = mid + 1; else hi = mid;
    }
    off[n] = lo;
}

// Final gather in sorted order: full-64B-line attr reads (quad-cooperative),
// purely sequential writes. Attr rows packed as bf16 (8 x bf16x2 = 32B).
__global__ __launch_bounds__(256) void gather_sorted_kernel(
    const uint2* __restrict__ sorted, const int* __restrict__ src,
    const float4* __restrict__ attr,
    int* __restrict__ srcS, uint2* __restrict__ attrS2) {
    int q = threadIdx.x & 3;                       // quarter of the row
    int row0 = blockIdx.x * 64 + (threadIdx.x >> 2);
    int stride = gridDim.x * 64;
    for (int p = row0; p < GE; p += stride) {
        int eid = (int)sorted[p].x;                // coalesced (4 lanes share line)
        float4 a = attr[(size_t)eid * 4 + q];      // 4 lanes cover one 64B line
        uint2 u;
        u.x = packbf2(a.x, a.y);
        u.y = packbf2(a.z, a.w);
        attrS2[(size_t)p * 4 + q] = u;             // sequential 8B/lane
        if (q == 0) srcS[p] = src[eid];            // sequential 4B, src via L3
    }
}

// ---------------- column stats on x (+ bf16 conversion of x) ----------------

__global__ __launch_bounds__(256) void col_stats64(const float* __restrict__ in,
                                                   float* __restrict__ sum,
                                                   float* __restrict__ sq,
                                                   unsigned short* __restrict__ outb) {
    int c = threadIdx.x & 63;
    int lr = threadIdx.x >> 6;
    float s = 0.f, q = 0.f;
    for (int r = blockIdx.x * 4 + lr; r < GN; r += gridDim.x * 4) {
        float v = in[(size_t)r * 64 + c];
        s += v;
        q += v * v;
        outb[(size_t)r * 64 + c] = bf16rn(v);
    }
    __shared__ float S[256];
    S[threadIdx.x] = s;
    __syncthreads();
    if (threadIdx.x < 64) {
        float a = S[threadIdx.x] + S[threadIdx.x + 64] + S[threadIdx.x + 128] + S[threadIdx.x + 192];
        atomicAdd(&sum[threadIdx.x], a);
    }
    __syncthreads();
    S[threadIdx.x] = q;
    __syncthreads();
    if (threadIdx.x < 64) {
        float a = S[threadIdx.x] + S[threadIdx.x + 64] + S[threadIdx.x + 128] + S[threadIdx.x + 192];
        atomicAdd(&sq[threadIdx.x], a);
    }
}

// ---------------- fused BN(pre) + GINE aggregation ----------------
// One wave per node (lane = feature). Uniform s_loads for src ids / attr rows;
// bf16 shift-decode + 16 fma per edge. Self term from the bf16 copy (hb).
// (Exact r9 body -- measured 84.2 us/dispatch.)

template <int LEAKY>
__global__ __launch_bounds__(256) void aggregate_kernel(
    const unsigned short* __restrict__ hb,  // bf16 features (gather + self)
    const float* __restrict__ sumv, const float* __restrict__ sqv,
    const float* __restrict__ bnw, const float* __restrict__ bnb,
    const int* __restrict__ off,
    const int* __restrict__ srcS,
    const unsigned* __restrict__ attrS,     // bf16-packed rows, 8 uints (32B) each
    const float* __restrict__ Wle, const float* __restrict__ ble,
    const float* __restrict__ epsArr, int layer,
    unsigned short* __restrict__ zb,        // bf16 output (gemm1 input)
    float* __restrict__ zeroBuf) {
    if (blockIdx.x == 0 && threadIdx.x < 128) zeroBuf[threadIdx.x] = 0.f;
    const int d = threadIdx.x & 63;
    const int node = __builtin_amdgcn_readfirstlane(blockIdx.x * 4 + (threadIdx.x >> 6));

    float mean = sumv[d] / FN;
    float var = sqv[d] / FN - mean * mean;
    float cA = rsqrtf(var + BN_EPS) * bnw[d];
    float cB = bnb[d] - mean * cA;

    float wq[16];
#pragma unroll
    for (int k = 0; k < 16; k += 4) {
        float4 t = *(const float4*)(Wle + d * 16 + k);
        wq[k] = t.x; wq[k + 1] = t.y; wq[k + 2] = t.z; wq[k + 3] = t.w;
    }
    float be = ble[d];
    float epsv = 1.0f + epsArr[layer];

    int p0 = off[node], p1 = off[node + 1];  // uniform -> s_load
    float hv = bfu16(hb[(((unsigned)node) << 6) + d]); // self term (bf16, L2)

    float acc = 0.0f;
    int p = p0;
    int pfull = p0 + ((p1 - p0) & ~7);
    for (; p < pfull; p += 8) {              // full groups: no masking
        int idx[8];
#pragma unroll
        for (int j = 0; j < 8; ++j) idx[j] = srcS[p + j];  // s_load (contiguous)
        float g[8];
#pragma unroll
        for (int j = 0; j < 8; ++j)
            g[j] = bfu16(hb[(((unsigned)idx[j]) << 6) + d]);  // 32-bit offset gathers
#pragma unroll
        for (int j = 0; j < 8; ++j) {
            const uint4* ar = (const uint4*)(attrS + (size_t)(p + j) * 8);
            uint4 A = ar[0], B = ar[1];      // uniform -> s_load / broadcast
            float e = be;
            e = fmaf(bflo(A.x), wq[0], e);  e = fmaf(bfhi(A.x), wq[1], e);
            e = fmaf(bflo(A.y), wq[2], e);  e = fmaf(bfhi(A.y), wq[3], e);
            e = fmaf(bflo(A.z), wq[4], e);  e = fmaf(bfhi(A.z), wq[5], e);
            e = fmaf(bflo(A.w), wq[6], e);  e = fmaf(bfhi(A.w), wq[7], e);
            e = fmaf(bflo(B.x), wq[8], e);  e = fmaf(bfhi(B.x), wq[9], e);
            e = fmaf(bflo(B.y), wq[10], e); e = fmaf(bfhi(B.y), wq[11], e);
            e = fmaf(bflo(B.z), wq[12], e); e = fmaf(bfhi(B.z), wq[13], e);
            e = fmaf(bflo(B.w), wq[14], e); e = fmaf(bfhi(B.w), wq[15], e);
            float gg = g[j] * cA + cB;
            if (LEAKY) gg = fmaxf(gg, 0.01f * gg);
            acc += fmaxf(gg + e, 0.f);
        }
    }
    for (; p < p1; p += 4) {                 // masked tail, groups of 4
        int idx[4];
#pragma unroll
        for (int j = 0; j < 4; ++j) {
            int q = p + j;
            if (q > p1 - 1) q = p1 - 1;
            idx[j] = srcS[q];
        }
        float g[4];
#pragma unroll
        for (int j = 0; j < 4; ++j)
            g[j] = bfu16(hb[(((unsigned)idx[j]) << 6) + d]);
#pragma unroll
        for (int j = 0; j < 4; ++j) {
            int q = p + j;
            if (q > p1 - 1) q = p1 - 1;
            const uint4* ar = (const uint4*)(attrS + (size_t)q * 8);
            uint4 A = ar[0], B = ar[1];
            float e = be;
            e = fmaf(bflo(A.x), wq[0], e);  e = fmaf(bfhi(A.x), wq[1], e);
            e = fmaf(bflo(A.y), wq[2], e);  e = fmaf(bfhi(A.y), wq[3], e);
            e = fmaf(bflo(A.z), wq[4], e);  e = fmaf(bfhi(A.z), wq[5], e);
            e = fmaf(bflo(A.w), wq[6], e);  e = fmaf(bfhi(A.w), wq[7], e);
            e = fmaf(bflo(B.x), wq[8], e);  e = fmaf(bfhi(B.x), wq[9], e);
            e = fmaf(bflo(B.y), wq[10], e); e = fmaf(bfhi(B.y), wq[11], e);
            e = fmaf(bflo(B.z), wq[12], e); e = fmaf(bfhi(B.z), wq[13], e);
            e = fmaf(bflo(B.w), wq[14], e); e = fmaf(bfhi(B.w), wq[15], e);
            float gg = g[j] * cA + cB;
            if (LEAKY) gg = fmaxf(gg, 0.01f * gg);
            float m = fmaxf(gg + e, 0.f);
            acc += (p + j < p1) ? m : 0.f;
        }
    }
    hv = hv * cA + cB;
    if (LEAKY) hv = fmaxf(hv, 0.01f * hv);
    zb[(size_t)node * 64 + d] = bf16rn(epsv * hv + acc);
}

// ---------------- MFMA bf16 GEMM: dst = f(src) @ W^T + bias [+resid] ----------------
// Block = 256 thr = 4 waves; tile 64 rows x 64 cols; grid-stride over row tiles.
// BN_IN+ABF16: bf16 input decoded + BN + leaky + repack. In-place src==dst is
// safe: each 64-row tile is owned by one block, and the block fully loads its
// A-fragments into registers before the epilogue writes the same rows.

template <bool BN_IN, bool ABF16, bool STATS, bool RESID, bool BF16OUT, bool F32OUT>
__global__ __launch_bounds__(256) void gemm_mfma(
    const float* __restrict__ srcf, const unsigned short* __restrict__ srcb, int src_ld,
    const unsigned short* __restrict__ Wb,   // bf16 [ncols][64]
    const float* __restrict__ bias,
    float* __restrict__ dst, int dst_ld,
    unsigned short* __restrict__ dstb, int dstb_ld,
    const float* __restrict__ resid,
    const float* __restrict__ statsInSum, const float* __restrict__ statsInSq,
    const float* __restrict__ bnw, const float* __restrict__ bnb,
    float* __restrict__ statsOutSum, float* __restrict__ statsOutSq,
    float* __restrict__ zeroBuf, int zeroN) {
    __shared__ float cA[64], cB[64];
    __shared__ float sS[64], sQ[64];
    int tid = threadIdx.x;
    if (zeroBuf && blockIdx.x == 0 && blockIdx.y == 0 && tid < zeroN) zeroBuf[tid] = 0.f;
    int c0 = blockIdx.y * 64;

    if (BN_IN) {
        if (tid < 64) {
            float m = statsInSum[tid] / FN;
            float v = statsInSq[tid] / FN - m * m;
            float a = rsqrtf(v + BN_EPS) * bnw[tid];
            cA[tid] = a;
            cB[tid] = bnb[tid] - m * a;
        }
        __syncthreads();
    }

    int w = tid >> 6, lane = tid & 63;
    int n16 = lane & 15, quad = lane >> 4;

    // B fragments once per block
    bf16x8 bfr[4][2];
#pragma unroll
    for (int t = 0; t < 4; ++t) {
        int col = c0 + t * 16 + n16;
        const unsigned short* bsrc = Wb + (size_t)col * 64 + quad * 8;
#pragma unroll
        for (int kk = 0; kk < 2; ++kk)
            bfr[t][kk] = *(const bf16x8*)(bsrc + kk * 32);
    }

    float ls[4] = {0.f, 0.f, 0.f, 0.f}, lq[4] = {0.f, 0.f, 0.f, 0.f};
    constexpr int NT = (GN + 63) / 64;  // 1563
    for (int tile = blockIdx.x; tile < NT; tile += gridDim.x) {
        int r0 = tile * 64;
        int arow = r0 + w * 16 + n16;
        int arc = arow < GN ? arow : 0;

        bf16x8 afr[2];
        if (ABF16 && !BN_IN) {
            const unsigned short* asrc = srcb + (size_t)arc * src_ld + quad * 8;
#pragma unroll
            for (int kk = 0; kk < 2; ++kk)
                afr[kk] = *(const bf16x8*)(asrc + kk * 32);
        } else if (ABF16 && BN_IN) {
            const unsigned short* asrc = srcb + (size_t)arc * src_ld + quad * 8;
#pragma unroll
            for (int kk = 0; kk < 2; ++kk) {
                uint4 rw = *(const uint4*)(asrc + kk * 32);
                float av[8] = {bflo(rw.x), bfhi(rw.x), bflo(rw.y), bfhi(rw.y),
                               bflo(rw.z), bfhi(rw.z), bflo(rw.w), bfhi(rw.w)};
                int kb = quad * 8 + kk * 32;
#pragma unroll
                for (int j = 0; j < 8; ++j) {
                    float t = av[j] * cA[kb + j] + cB[kb + j];
                    av[j] = fmaxf(t, 0.01f * t);
                }
                uint4 fu;
                fu.x = packbf2(av[0], av[1]); fu.y = packbf2(av[2], av[3]);
                fu.z = packbf2(av[4], av[5]); fu.w = packbf2(av[6], av[7]);
                afr[kk] = __builtin_bit_cast(bf16x8, fu);
            }
        } else {
            const float* asrc = srcf + (size_t)arc * src_ld + quad * 8;
#pragma unroll
            for (int kk = 0; kk < 2; ++kk) {
                const float4* p = (const float4*)(asrc + kk * 32);
                float4 x0 = p[0], x1 = p[1];
                float av[8] = {x0.x, x0.y, x0.z, x0.w, x1.x, x1.y, x1.z, x1.w};
                if (BN_IN) {
                    int kb = quad * 8 + kk * 32;
#pragma unroll
                    for (int j = 0; j < 8; ++j) {
                        float t = av[j] * cA[kb + j] + cB[kb + j];
                        av[j] = fmaxf(t, 0.01f * t);
                    }
                }
                uint4 fu;
                fu.x = packbf2(av[0], av[1]); fu.y = packbf2(av[2], av[3]);
                fu.z = packbf2(av[4], av[5]); fu.w = packbf2(av[6], av[7]);
                afr[kk] = __builtin_bit_cast(bf16x8, fu);
            }
        }

        f32x4 acc[4] = {{0.f, 0.f, 0.f, 0.f}, {0.f, 0.f, 0.f, 0.f},
                        {0.f, 0.f, 0.f, 0.f}, {0.f, 0.f, 0.f, 0.f}};
#pragma unroll
        for (int t = 0; t < 4; ++t) {
            acc[t] = __builtin_amdgcn_mfma_f32_16x16x32_bf16(afr[0], bfr[t][0], acc[t], 0, 0, 0);
            acc[t] = __builtin_amdgcn_mfma_f32_16x16x32_bf16(afr[1], bfr[t][1], acc[t], 0, 0, 0);
        }

        // epilogue: D row = r0 + w*16 + quad*4 + r, col = c0 + t*16 + n16
#pragma unroll
        for (int t = 0; t < 4; ++t) {
            int col = c0 + t * 16 + n16;
            float bv = bias[col];
#pragma unroll
            for (int r = 0; r < 4; ++r) {
                int row = r0 + w * 16 + quad * 4 + r;
                if (row < GN) {
                    float o = acc[t][r] + bv;
                    if (RESID) o += resid[(size_t)row * dst_ld + col];
                    if (F32OUT) dst[(size_t)row * dst_ld + col] = o;
                    if (BF16OUT) dstb[(size_t)row * dstb_ld + col] = bf16rn(o);
                    if (STATS) {
                        float oS = o;
                        if (BF16OUT && !F32OUT) oS = bfu16(bf16rn(o));  // stats match stored data
                        ls[t] += oS;
                        lq[t] += oS * oS;
                    }
                }
            }
        }
    }

    if (STATS) {
        if (tid < 64) { sS[tid] = 0.f; sQ[tid] = 0.f; }
        __syncthreads();
#pragma unroll
        for (int t = 0; t < 4; ++t) {
            float s = ls[t], q = lq[t];
            s += __shfl_down(s, 16, 64); s += __shfl_down(s, 32, 64);
            q += __shfl_down(q, 16, 64); q += __shfl_down(q, 32, 64);
            if (lane < 16) {
                atomicAdd(&sS[t * 16 + n16], s);
                atomicAdd(&sQ[t * 16 + n16], q);
            }
        }
        __syncthreads();
        if (tid < 64) {
            atomicAdd(&statsOutSum[c0 + tid], sS[tid]);
            atomicAdd(&statsOutSq[c0 + tid], sQ[tid]);
        }
    }
}

// ---------------- classifier tail (bf16 y1) ----------------

__global__ __launch_bounds__(256) void cls2_kernel(
    const unsigned short* __restrict__ y1b,
    const float* __restrict__ sum, const float* __restrict__ sq,
    const float* __restrict__ bnw, const float* __restrict__ bnb,
    const float* __restrict__ w2, const float* __restrict__ b2,
    float* __restrict__ out) {
    int node = blockIdx.x * 4 + (threadIdx.x >> 6);
    int d = threadIdx.x & 63;
    if (node >= GN) return;
    float partial = 0.f;
#pragma unroll
    for (int hh = 0; hh < 2; ++hh) {
        int c = d + hh * 64;
        float m = sum[c] / FN;
        float var = sq[c] / FN - m * m;
        float a = rsqrtf(var + BN_EPS) * bnw[c];
        float v = bfu16(y1b[(size_t)node * 128 + c]);
        v = v * a + (bnb[c] - m * a);
        v = fmaxf(v, 0.01f * v);
        partial += v * w2[c];
    }
    for (int o = 32; o >= 1; o >>= 1) partial += __shfl_down(partial, o, 64);
    if (d == 0) out[node] = partial + b2[0];
}

// ---------------- launcher ----------------

extern "C" void kernel_launch(void* const* d_in, const int* in_sizes, int n_in,
                              void* d_out, int out_size, void* d_ws, size_t ws_size,
                              hipStream_t stream) {
    (void)in_sizes; (void)n_in; (void)out_size; (void)ws_size;
    const float* x    = (const float*)d_in[0];
    const int*   ei   = (const int*)d_in[1];
    const float* attr = (const float*)d_in[2];
    const float* bnpw = (const float*)d_in[3];
    const float* bnpb = (const float*)d_in[4];
    const float* elw  = (const float*)d_in[5];
    const float* elb  = (const float*)d_in[6];
    const float* l1w  = (const float*)d_in[7];
    const float* l1b  = (const float*)d_in[8];
    const float* bnmw = (const float*)d_in[9];
    const float* bnmb = (const float*)d_in[10];
    const float* l2w  = (const float*)d_in[11];
    const float* l2b  = (const float*)d_in[12];
    const float* epsA = (const float*)d_in[13];
    const float* c1w  = (const float*)d_in[14];
    const float* c1b  = (const float*)d_in[15];
    const float* cbw  = (const float*)d_in[16];
    const float* cbb  = (const float*)d_in[17];
    const float* c2w  = (const float*)d_in[18];
    const float* c2b  = (const float*)d_in[19];
    const int* srcArr = ei;
    const int* dstArr = ei + GE;

    char* base = (char*)d_ws;
    size_t ofs = 0;
    auto alloc = [&](size_t bytes) {
        void* p = base + ofs;
        ofs = (ofs + bytes + 1023) & ~(size_t)1023;
        return p;
    };
    // EXACT r9 allocation order/sizes -- no new buffers (layout-coupling test).
    int* off              = (int*)alloc((size_t)(GN + 1) * 4);
    int* hist1            = (int*)alloc((size_t)256 * SB * 4);
    int* hist2            = (int*)alloc((size_t)512 * SB * 4);
    int* binTot1          = (int*)alloc(512 * 4);
    int* binTot2          = (int*)alloc(512 * 4);
    int* src_sorted       = (int*)alloc((size_t)GE * 4);
    unsigned* attr_sorted = (unsigned*)alloc((size_t)GE * 32);  // bf16 rows, 32B
    unsigned short* wbf   = (unsigned short*)alloc(40960 * 2);
    float* stP0 = (float*)alloc(512);
    float* stP1 = (float*)alloc(512);
    float* stM  = (float*)alloc(512);
    float* stC  = (float*)alloc(1024);
    float* h = (float*)alloc((size_t)GN * 256);
    float* z = (float*)alloc((size_t)GN * 256);   // only aliased by sort pairs
    unsigned short* zb = (unsigned short*)alloc((size_t)GN * 128);
    unsigned short* xb = (unsigned short*)alloc((size_t)GN * 128);
    unsigned short* hb = (unsigned short*)alloc((size_t)GN * 128);
    unsigned short* y1b = (unsigned short*)attr_sorted;  // reuse (25.6MB <= 51.2MB)
    // Radix ping-pong pairs alias z (25.6MB = 2 x GE*8B).
    uint2* pairsA = (uint2*)z;
    uint2* pairsB = (uint2*)((char*)z + (size_t)GE * 8);

    float* stP[2] = {stP0, stP1};

    // ---- deterministic 2-pass radix sort by dst (no global atomics) ----
    h1_kernel<<<SB, 256, 0, stream>>>(dstArr, hist1, l1w, l2w, c1w, wbf, stP0);
    s1_kernel<<<256, 256, 0, stream>>>(hist1, binTot1);
    s2_kernel<<<1, 256, 0, stream>>>(binTot1, 256);
    scat1_kernel<<<SB, 256, 0, stream>>>(dstArr, hist1, binTot1, pairsA);
    h2_kernel<<<SB, 256, 0, stream>>>(pairsA, hist2);
    s1_kernel<<<512, 256, 0, stream>>>(hist2, binTot2);
    s2_kernel<<<1, 256, 0, stream>>>(binTot2, 512);
    scat2_kernel<<<SB, 256, 0, stream>>>(pairsA, hist2, binTot2, pairsB);
    off_kernel<<<392, 256, 0, stream>>>(pairsB, off);
    gather_sorted_kernel<<<4096, 256, 0, stream>>>(pairsB, srcArr, (const float4*)attr,
                                                   src_sorted, (uint2*)attr_sorted);

    // ---- layer-0 pre-BN stats on x (+ x -> bf16) ----
    col_stats64<<<512, 256, 0, stream>>>(x, stP0, stP0 + 64, xb);

    const unsigned short* hbsrc = xb;
    for (int i = 0; i < 4; ++i) {
        float* sIn = stP[i & 1];
        float* sNext = stP[(i + 1) & 1];
        if (i == 0)
            aggregate_kernel<0><<<25000, 256, 0, stream>>>(
                hbsrc, sIn, sIn + 64, bnpw + i * 64, bnpb + i * 64,
                off, src_sorted, attr_sorted, elw + i * 1024, elb + i * 64, epsA, i,
                zb, stM);
        else
            aggregate_kernel<1><<<25000, 256, 0, stream>>>(
                hbsrc, sIn, sIn + 64, bnpw + i * 64, bnpb + i * 64,
                off, src_sorted, attr_sorted, elw + i * 1024, elb + i * 64, epsA, i,
                zb, stM);
        // gemm1 IN-PLACE on zb: zb = zb @ l1w^T + b (bf16); stats on rounded.
        gemm_mfma<false, true, true, false, true, false><<<dim3(782, 1), 256, 0, stream>>>(
            nullptr, zb, 64, wbf + i * 4096, l1b + i * 64, nullptr, 0, zb, 64, nullptr,
            nullptr, nullptr, nullptr, nullptr, stM, stM + 64,
            (i == 3) ? stC : sNext, (i == 3) ? 256 : 128);
        // gemm2: h = leaky(bn(zb)) @ l2w^T + b [+h] ; stats -> sNext ; bf16 copy
        if (i == 0)
            gemm_mfma<true, true, true, false, true, true><<<dim3(782, 1), 256, 0, stream>>>(
                nullptr, zb, 64, wbf + 16384 + i * 4096, l2b + i * 64, h, 64, hb, 64,
                nullptr, stM, stM + 64, bnmw + i * 64, bnmb + i * 64,
                sNext, sNext + 64, nullptr, 0);
        else if (i < 3)
            gemm_mfma<true, true, true, true, true, true><<<dim3(782, 1), 256, 0, stream>>>(
                nullptr, zb, 64, wbf + 16384 + i * 4096, l2b + i * 64, h, 64, hb, 64,
                h, stM, stM + 64, bnmw + i * 64, bnmb + i * 64,
                sNext, sNext + 64, nullptr, 0);
        else
            gemm_mfma<true, true, false, true, true, true><<<dim3(782, 1), 256, 0, stream>>>(
                nullptr, zb, 64, wbf + 16384 + i * 4096, l2b + i * 64, h, 64, hb, 64,
                h, stM, stM + 64, bnmw + i * 64, bnmb + i * 64,
                nullptr, nullptr, nullptr, 0);
        hbsrc = hb;
    }

    // ---- classifier: y1b = hb @ c1w^T + b (bf16 out only), then BN+leaky+dot ----
    dim3 gc(391, 2);
    gemm_mfma<false, true, true, false, true, false><<<gc, 256, 0, stream>>>(
        nullptr, hb, 64, wbf + 32768, c1b, nullptr, 128, y1b, 128, nullptr,
        nullptr, nullptr, nullptr, nullptr, stC, stC + 128, nullptr, 0);
    cls2_kernel<<<25000, 256, 0, stream>>>(y1b, stC, stC + 128, cbw, cbb, c2w, c2b,
                                           (float*)d_out);
}

// Round 14
// 934.706 us; speedup vs baseline: 1.0839x; 1.0788x over previous
//
#include <hip/hip_runtime.h>
#include <hip/hip_bf16.h>
#include <hip/hip_fp16.h>

// Problem constants (fixed by reference)
constexpr int GN = 100000;   // nodes
constexpr int GE = 1600000;  // edges
constexpr float FN = 100000.0f;
constexpr float BN_EPS = 1e-5f;

// Radix sort geometry: 2-pass LSD on dst (17 bits): low 8, then high 9.
constexpr int SB = 512;                   // sort blocks per pass
constexpr int TILE = (GE + SB - 1) / SB;  // 3125 edges per block (exact: 512*3125=GE)

typedef __attribute__((ext_vector_type(8))) short bf16x8;
typedef __attribute__((ext_vector_type(4))) float f32x4;

#if __has_builtin(__builtin_amdgcn_fdot2)
#define HAVE_FDOT2 1
typedef _Float16 h2v __attribute__((ext_vector_type(2)));
#else
#define HAVE_FDOT2 0
#endif

__device__ __forceinline__ unsigned packbf2(float a, float b) {
    __hip_bfloat162 h = __float22bfloat162_rn(float2{a, b});
    union { __hip_bfloat162 h2; unsigned u; } cv;
    cv.h2 = h;
    return cv.u;
}

__device__ __forceinline__ unsigned packh2(float a, float b) {
    __half2 h = __floats2half2_rn(a, b);
    union { __half2 h2; unsigned u; } cv;
    cv.h2 = h;
    return cv.u;
}

__device__ __forceinline__ unsigned short bf16rn(float f) {
    unsigned u = __builtin_bit_cast(unsigned, f);
    unsigned r = (u + 0x7FFF + ((u >> 16) & 1)) >> 16;
    return (unsigned short)r;
}

__device__ __forceinline__ float bflo(unsigned u) {
    return __builtin_bit_cast(float, u << 16);
}
__device__ __forceinline__ float bfhi(unsigned u) {
    return __builtin_bit_cast(float, u & 0xFFFF0000u);
}
__device__ __forceinline__ float bfu16(unsigned short u) {
    return __builtin_bit_cast(float, (unsigned)u << 16);
}

// Bijective block permutation: adjacent chunk slots j, j+1 (same j>>6) map to
// blocks with equal b&7 == same XCD under round-robin dispatch, so adjacent
// output chunks are written XCD-locally (lines merge in that XCD's L2).
__device__ __forceinline__ int permb(int b) { return ((b & 7) << 6) | (b >> 3); }

// ---------------- radix sort of {eid, dst} by dst ----------------

// Pass-1 histogram (dst & 255) + folded weight bf16 conversion + stats zero.
__global__ __launch_bounds__(256) void h1_kernel(const int* __restrict__ dst,
                                                 int* __restrict__ hist1,
                                                 const float* __restrict__ l1w,
                                                 const float* __restrict__ l2w,
                                                 const float* __restrict__ c1w,
                                                 unsigned short* __restrict__ wb,
                                                 float* __restrict__ zeroBuf) {
    __shared__ int cnt[256];
    int b = blockIdx.x, t = threadIdx.x;
    if (b == 0 && t < 128) zeroBuf[t] = 0.f;
    cnt[t] = 0;
    __syncthreads();
    int e0 = b * TILE, e1 = min(e0 + TILE, GE);
    for (int i = e0 + t; i < e1; i += 256)
        atomicAdd(&cnt[dst[i] & 255], 1);
    __syncthreads();
    hist1[t * SB + permb(b)] = cnt[t];  // bin-major, XCD-grouped chunk order
    for (int i = b * 256 + t; i < 40960; i += SB * 256) {
        float v;
        if (i < 16384) v = l1w[i];
        else if (i < 32768) v = l2w[i - 16384];
        else v = c1w[i - 32768];
        wb[i] = bf16rn(v);
    }
}

// Within-bin exclusive prefix across the SB block-chunks; bin total out.
__global__ __launch_bounds__(256) void s1_kernel(int* __restrict__ hist,
                                                 int* __restrict__ binTot) {
    int bin = blockIdx.x, t = threadIdx.x;
    int v0 = hist[bin * SB + 2 * t], v1 = hist[bin * SB + 2 * t + 1];
    int s = v0 + v1;
    int lane = t & 63, w = t >> 6;
    int incl = s;
    for (int o = 1; o < 64; o <<= 1) {
        int u = __shfl_up(incl, o, 64);
        if (lane >= o) incl += u;
    }
    __shared__ int ws_[4];
    if (lane == 63) ws_[w] = incl;
    __syncthreads();
    int wb = 0;
#pragma unroll
    for (int k = 0; k < 4; ++k)
        if (k < w) wb += ws_[k];
    int ex = wb + incl - s;
    hist[bin * SB + 2 * t] = ex;
    hist[bin * SB + 2 * t + 1] = ex + v0;
    if (t == 255) binTot[bin] = ex + s;
}

// In-place exclusive scan of n<=512 bin totals (1 block).
__global__ __launch_bounds__(256) void s2_kernel(int* __restrict__ a, int n) {
    int t = threadIdx.x;
    int v0 = (2 * t < n) ? a[2 * t] : 0;
    int v1 = (2 * t + 1 < n) ? a[2 * t + 1] : 0;
    int s = v0 + v1;
    int lane = t & 63, w = t >> 6;
    int incl = s;
    for (int o = 1; o < 64; o <<= 1) {
        int u = __shfl_up(incl, o, 64);
        if (lane >= o) incl += u;
    }
    __shared__ int ws_[4];
    if (lane == 63) ws_[w] = incl;
    __syncthreads();
    int wb = 0;
#pragma unroll
    for (int k = 0; k < 4; ++k)
        if (k < w) wb += ws_[k];
    int ex = wb + incl - s;
    if (2 * t < n) a[2 * t] = ex;
    if (2 * t + 1 < n) a[2 * t + 1] = ex + v0;
}

// Pass-1 scatter (need not be stable): LDS cursors, no global atomics.
__global__ __launch_bounds__(256) void scat1_kernel(const int* __restrict__ dst,
                                                    const int* __restrict__ hist1,
                                                    const int* __restrict__ binBase1,
                                                    uint2* __restrict__ out) {
    __shared__ int base[256];
    int b = blockIdx.x, t = threadIdx.x;
    base[t] = hist1[t * SB + permb(b)] + binBase1[t];
    __syncthreads();
    int e0 = b * TILE, e1 = min(e0 + TILE, GE);
    for (int i = e0 + t; i < e1; i += 256) {
        int dv = dst[i];
        int pos = atomicAdd(&base[dv & 255], 1);  // LDS atomic only
        uint2 pr;
        pr.x = (unsigned)i;
        pr.y = (unsigned)dv;
        out[pos] = pr;
    }
}

// Pass-2 histogram (dst >> 8, 512 bins). Stability: block b processes input
// tile tp = permb(b) and writes counts at chunk slot tp, so chunk order in
// every bin == input tile order (stable) with XCD-local adjacent chunks.
__global__ __launch_bounds__(256) void h2_kernel(const uint2* __restrict__ in,
                                                 int* __restrict__ hist2) {
    __shared__ int cnt[512];
    int b = blockIdx.x, t = threadIdx.x;
    int tp = permb(b);
    cnt[t] = 0;
    cnt[t + 256] = 0;
    __syncthreads();
    int e0 = tp * TILE, e1 = min(e0 + TILE, GE);
    for (int i = e0 + t; i < e1; i += 256)
        atomicAdd(&cnt[in[i].y >> 8], 1);
    __syncthreads();
    hist2[t * SB + tp] = cnt[t];
    hist2[(t + 256) * SB + tp] = cnt[t + 256];
}

// Pass-2 scatter: stable (block b reads tile permb(b), writes chunk slot
// permb(b); within-block order preserved by wave-serialized sub-steps and
// in-wave ballot rank). No global atomics.
__global__ __launch_bounds__(256) void scat2_kernel(const uint2* __restrict__ in,
                                                    const int* __restrict__ hist2,
                                                    const int* __restrict__ binBase2,
                                                    uint2* __restrict__ out) {
    __shared__ int base[512];
    int b = blockIdx.x, t = threadIdx.x;
    int tp = permb(b);
    base[t] = hist2[t * SB + tp] + binBase2[t];
    base[t + 256] = hist2[(t + 256) * SB + tp] + binBase2[t + 256];
    __syncthreads();
    int e0 = tp * TILE, e1 = min(e0 + TILE, GE);
    int lane = t & 63, w = t >> 6;
    unsigned long long below = (1ull << lane) - 1ull;
    if (lane == 63) below = ~0ull >> 1;
    for (int r = e0; r < e1; r += 256) {
        int i = r + t;
        bool valid = (i < e1);
        uint2 el;
        el.x = 0u; el.y = 0u;
        if (valid) el = in[i];
        int bin = (int)(el.y >> 8);
        unsigned long long m = __ballot(valid);
#pragma unroll
        for (int bb = 0; bb < 9; ++bb) {
            unsigned long long bm = __ballot((bin >> bb) & 1);
            m &= ((bin >> bb) & 1) ? bm : ~bm;
        }
        int rank = __popcll(m & below);
        int cntm = __popcll(m);
        bool leader = valid && ((m & below) == 0ull);
#pragma unroll
        for (int ws = 0; ws < 4; ++ws) {
            if (w == ws && valid) {
                int p0 = base[bin];                 // all group lanes read (pre-write)
                if (leader) base[bin] = p0 + cntm;  // unique leader per bin
                out[p0 + rank] = el;
            }
            __syncthreads();
        }
    }
}

// CSR offsets by binary search in sorted dst (replaces hist+scan chain).
__global__ __launch_bounds__(256) void off_kernel(const uint2* __restrict__ sorted,
                                                  int* __restrict__ off) {
    int n = blockIdx.x * 256 + threadIdx.x;
    if (n > GN) return;
    if (n == GN) { off[GN] = GE; return; }
    int lo = 0, hi = GE;
    while (lo < hi) {
        int mid = (lo + hi) >> 1;
        if ((int)sorted[mid].y < n) lo = mid + 1; else hi = mid;
    }
    off[n] = lo;
}

// Final gather in sorted order: full-64B-line attr reads (quad-cooperative),
// purely sequential writes. Attr rows packed as f16 (dot2 path) or bf16.
__global__ __launch_bounds__(256) void gather_sorted_kernel(
    const uint2* __restrict__ sorted, const int* __restrict__ src,
    const float4* __restrict__ attr,
    int* __restrict__ srcS, uint2* __restrict__ attrS2) {
    int q = threadIdx.x & 3;                       // quarter of the row
    int row0 = blockIdx.x * 64 + (threadIdx.x >> 2);
    int stride = gridDim.x * 64;
    for (int p = row0; p < GE; p += stride) {
        int eid = (int)sorted[p].x;                // coalesced (4 lanes share line)
        float4 a = attr[(size_t)eid * 4 + q];      // 4 lanes cover one 64B line
        uint2 u;
#if HAVE_FDOT2
        u.x = packh2(a.x, a.y);
        u.y = packh2(a.z, a.w);
#else
        u.x = packbf2(a.x, a.y);
        u.y = packbf2(a.z, a.w);
#endif
        attrS2[(size_t)p * 4 + q] = u;             // sequential 8B/lane
        if (q == 0) srcS[p] = src[eid];            // sequential 4B, src via L3
    }
}

// ---------------- column stats on x (+ bf16 conversion of x) ----------------

__global__ __launch_bounds__(256) void col_stats64(const float* __restrict__ in,
                                                   float* __restrict__ sum,
                                                   float* __restrict__ sq,
                                                   unsigned short* __restrict__ outb) {
    int c = threadIdx.x & 63;
    int lr = threadIdx.x >> 6;
    float s = 0.f, q = 0.f;
    for (int r = blockIdx.x * 4 + lr; r < GN; r += gridDim.x * 4) {
        float v = in[(size_t)r * 64 + c];
        s += v;
        q += v * v;
        outb[(size_t)r * 64 + c] = bf16rn(v);
    }
    __shared__ float S[256];
    S[threadIdx.x] = s;
    __syncthreads();
    if (threadIdx.x < 64) {
        float a = S[threadIdx.x] + S[threadIdx.x + 64] + S[threadIdx.x + 128] + S[threadIdx.x + 192];
        atomicAdd(&sum[threadIdx.x], a);
    }
    __syncthreads();
    S[threadIdx.x] = q;
    __syncthreads();
    if (threadIdx.x < 64) {
        float a = S[threadIdx.x] + S[threadIdx.x + 64] + S[threadIdx.x + 128] + S[threadIdx.x + 192];
        atomicAdd(&sq[threadIdx.x], a);
    }
}

// ---------------- fused BN(pre) + GINE aggregation ----------------
// One wave per node (lane = feature). Uniform s_loads for src ids / attr rows;
// dot via v_dot2_f32_f16 (8 instrs, no decode) when available, else
// bf16 shift-decode + 16 fma. Self term read from the bf16 copy (hb) --
// drops the 25.6MB/layer fp32 stream; bf16 rounding is within threshold.

template <int LEAKY>
__global__ __launch_bounds__(256) void aggregate_kernel(
    const unsigned short* __restrict__ hb,  // bf16 features (gather + self)
    const float* __restrict__ sumv, const float* __restrict__ sqv,
    const float* __restrict__ bnw, const float* __restrict__ bnb,
    const int* __restrict__ off,
    const int* __restrict__ srcS,
    const unsigned* __restrict__ attrS,     // packed rows, 8 uints (32B) each
    const float* __restrict__ Wle, const float* __restrict__ ble,
    const float* __restrict__ epsArr, int layer,
    unsigned short* __restrict__ zb,        // bf16 output (gemm1 input)
    float* __restrict__ zeroBuf) {
    if (blockIdx.x == 0 && threadIdx.x < 128) zeroBuf[threadIdx.x] = 0.f;
    const int d = threadIdx.x & 63;
    const int node = __builtin_amdgcn_readfirstlane(blockIdx.x * 4 + (threadIdx.x >> 6));

    float mean = sumv[d] / FN;
    float var = sqv[d] / FN - mean * mean;
    float cA = rsqrtf(var + BN_EPS) * bnw[d];
    float cB = bnb[d] - mean * cA;

#if HAVE_FDOT2
    h2v wq[8];
#pragma unroll
    for (int k = 0; k < 8; ++k) {
        float2 t = *(const float2*)(Wle + d * 16 + k * 2);
        h2v v = {(_Float16)t.x, (_Float16)t.y};
        wq[k] = v;
    }
#else
    float wq[16];
#pragma unroll
    for (int k = 0; k < 16; k += 4) {
        float4 t = *(const float4*)(Wle + d * 16 + k);
        wq[k] = t.x; wq[k + 1] = t.y; wq[k + 2] = t.z; wq[k + 3] = t.w;
    }
#endif
    float be = ble[d];
    float epsv = 1.0f + epsArr[layer];

    int p0 = off[node], p1 = off[node + 1];            // uniform -> s_load
    float hv = bfu16(hb[(((unsigned)node) << 6) + d]); // self term (bf16, L2)

    float acc = 0.0f;
    int p = p0;
    int pfull = p0 + ((p1 - p0) & ~7);
    for (; p < pfull; p += 8) {              // full groups: no masking
        int idx[8];
#pragma unroll
        for (int j = 0; j < 8; ++j) idx[j] = srcS[p + j];  // s_load (contiguous)
        float g[8];
#pragma unroll
        for (int j = 0; j < 8; ++j)
            g[j] = bfu16(hb[(((unsigned)idx[j]) << 6) + d]);  // 32-bit offset gathers
#pragma unroll
        for (int j = 0; j < 8; ++j) {
            const uint4* ar = (const uint4*)(attrS + (size_t)(p + j) * 8);
            uint4 A = ar[0], B = ar[1];      // uniform -> s_load / broadcast
            float e = be;
#if HAVE_FDOT2
            e = __builtin_amdgcn_fdot2(__builtin_bit_cast(h2v, A.x), wq[0], e, false);
            e = __builtin_amdgcn_fdot2(__builtin_bit_cast(h2v, A.y), wq[1], e, false);
            e = __builtin_amdgcn_fdot2(__builtin_bit_cast(h2v, A.z), wq[2], e, false);
            e = __builtin_amdgcn_fdot2(__builtin_bit_cast(h2v, A.w), wq[3], e, false);
            e = __builtin_amdgcn_fdot2(__builtin_bit_cast(h2v, B.x), wq[4], e, false);
            e = __builtin_amdgcn_fdot2(__builtin_bit_cast(h2v, B.y), wq[5], e, false);
            e = __builtin_amdgcn_fdot2(__builtin_bit_cast(h2v, B.z), wq[6], e, false);
            e = __builtin_amdgcn_fdot2(__builtin_bit_cast(h2v, B.w), wq[7], e, false);
#else
            e = fmaf(bflo(A.x), wq[0], e);  e = fmaf(bfhi(A.x), wq[1], e);
            e = fmaf(bflo(A.y), wq[2], e);  e = fmaf(bfhi(A.y), wq[3], e);
            e = fmaf(bflo(A.z), wq[4], e);  e = fmaf(bfhi(A.z), wq[5], e);
            e = fmaf(bflo(A.w), wq[6], e);  e = fmaf(bfhi(A.w), wq[7], e);
            e = fmaf(bflo(B.x), wq[8], e);  e = fmaf(bfhi(B.x), wq[9], e);
            e = fmaf(bflo(B.y), wq[10], e); e = fmaf(bfhi(B.y), wq[11], e);
            e = fmaf(bflo(B.z), wq[12], e); e = fmaf(bfhi(B.z), wq[13], e);
            e = fmaf(bflo(B.w), wq[14], e); e = fmaf(bfhi(B.w), wq[15], e);
#endif
            float gg = g[j] * cA + cB;
            if (LEAKY) gg = fmaxf(gg, 0.01f * gg);
            acc += fmaxf(gg + e, 0.f);
        }
    }
    for (; p < p1; p += 4) {                 // masked tail, groups of 4
        int idx[4];
#pragma unroll
        for (int j = 0; j < 4; ++j) {
            int q = p + j;
            if (q > p1 - 1) q = p1 - 1;
            idx[j] = srcS[q];
        }
        float g[4];
#pragma unroll
        for (int j = 0; j < 4; ++j)
            g[j] = bfu16(hb[(((unsigned)idx[j]) << 6) + d]);
#pragma unroll
        for (int j = 0; j < 4; ++j) {
            int q = p + j;
            if (q > p1 - 1) q = p1 - 1;
            const uint4* ar = (const uint4*)(attrS + (size_t)q * 8);
            uint4 A = ar[0], B = ar[1];
            float e = be;
#if HAVE_FDOT2
            e = __builtin_amdgcn_fdot2(__builtin_bit_cast(h2v, A.x), wq[0], e, false);
            e = __builtin_amdgcn_fdot2(__builtin_bit_cast(h2v, A.y), wq[1], e, false);
            e = __builtin_amdgcn_fdot2(__builtin_bit_cast(h2v, A.z), wq[2], e, false);
            e = __builtin_amdgcn_fdot2(__builtin_bit_cast(h2v, A.w), wq[3], e, false);
            e = __builtin_amdgcn_fdot2(__builtin_bit_cast(h2v, B.x), wq[4], e, false);
            e = __builtin_amdgcn_fdot2(__builtin_bit_cast(h2v, B.y), wq[5], e, false);
            e = __builtin_amdgcn_fdot2(__builtin_bit_cast(h2v, B.z), wq[6], e, false);
            e = __builtin_amdgcn_fdot2(__builtin_bit_cast(h2v, B.w), wq[7], e, false);
#else
            e = fmaf(bflo(A.x), wq[0], e);  e = fmaf(bfhi(A.x), wq[1], e);
            e = fmaf(bflo(A.y), wq[2], e);  e = fmaf(bfhi(A.y), wq[3], e);
            e = fmaf(bflo(A.z), wq[4], e);  e = fmaf(bfhi(A.z), wq[5], e);
            e = fmaf(bflo(A.w), wq[6], e);  e = fmaf(bfhi(A.w), wq[7], e);
            e = fmaf(bflo(B.x), wq[8], e);  e = fmaf(bfhi(B.x), wq[9], e);
            e = fmaf(bflo(B.y), wq[10], e); e = fmaf(bfhi(B.y), wq[11], e);
            e = fmaf(bflo(B.z), wq[12], e); e = fmaf(bfhi(B.z), wq[13], e);
            e = fmaf(bflo(B.w), wq[14], e); e = fmaf(bfhi(B.w), wq[15], e);
#endif
            float gg = g[j] * cA + cB;
            if (LEAKY) gg = fmaxf(gg, 0.01f * gg);
            float m = fmaxf(gg + e, 0.f);
            acc += (p + j < p1) ? m : 0.f;
        }
    }
    hv = hv * cA + cB;
    if (LEAKY) hv = fmaxf(hv, 0.01f * hv);
    zb[(size_t)node * 64 + d] = bf16rn(epsv * hv + acc);
}

// ---------------- MFMA bf16 GEMM: dst = f(src) @ W^T + bias [+resid] ----------------
// Block = 256 thr = 4 waves; tile 64 rows x 64 cols; grid-stride over row tiles.

template <bool BN_IN, bool ABF16, bool STATS, bool RESID, bool BF16OUT, bool F32OUT>
__global__ __launch_bounds__(256) void gemm_mfma(
    const float* __restrict__ srcf, const unsigned short* __restrict__ srcb, int src_ld,
    const unsigned short* __restrict__ Wb,   // bf16 [ncols][64]
    const float* __restrict__ bias,
    float* __restrict__ dst, int dst_ld,
    unsigned short* __restrict__ dstb, int dstb_ld,
    const float* __restrict__ resid,
    const float* __restrict__ statsInSum, const float* __restrict__ statsInSq,
    const float* __restrict__ bnw, const float* __restrict__ bnb,
    float* __restrict__ statsOutSum, float* __restrict__ statsOutSq,
    float* __restrict__ zeroBuf, int zeroN) {
    __shared__ float cA[64], cB[64];
    __shared__ float sS[64], sQ[64];
    int tid = threadIdx.x;
    if (zeroBuf && blockIdx.x == 0 && blockIdx.y == 0 && tid < zeroN) zeroBuf[tid] = 0.f;
    int c0 = blockIdx.y * 64;

    if (BN_IN) {
        if (tid < 64) {
            float m = statsInSum[tid] / FN;
            float v = statsInSq[tid] / FN - m * m;
            float a = rsqrtf(v + BN_EPS) * bnw[tid];
            cA[tid] = a;
            cB[tid] = bnb[tid] - m * a;
        }
        __syncthreads();
    }

    int w = tid >> 6, lane = tid & 63;
    int n16 = lane & 15, quad = lane >> 4;

    // B fragments once per block
    bf16x8 bfr[4][2];
#pragma unroll
    for (int t = 0; t < 4; ++t) {
        int col = c0 + t * 16 + n16;
        const unsigned short* bsrc = Wb + (size_t)col * 64 + quad * 8;
#pragma unroll
        for (int kk = 0; kk < 2; ++kk)
            bfr[t][kk] = *(const bf16x8*)(bsrc + kk * 32);
    }

    float ls[4] = {0.f, 0.f, 0.f, 0.f}, lq[4] = {0.f, 0.f, 0.f, 0.f};
    constexpr int NT = (GN + 63) / 64;  // 1563
    for (int tile = blockIdx.x; tile < NT; tile += gridDim.x) {
        int r0 = tile * 64;
        int arow = r0 + w * 16 + n16;
        int arc = arow < GN ? arow : 0;

        bf16x8 afr[2];
        if (ABF16) {
            const unsigned short* asrc = srcb + (size_t)arc * src_ld + quad * 8;
#pragma unroll
            for (int kk = 0; kk < 2; ++kk)
                afr[kk] = *(const bf16x8*)(asrc + kk * 32);
        } else {
            const float* asrc = srcf + (size_t)arc * src_ld + quad * 8;
#pragma unroll
            for (int kk = 0; kk < 2; ++kk) {
                const float4* p = (const float4*)(asrc + kk * 32);
                float4 x0 = p[0], x1 = p[1];
                float av[8] = {x0.x, x0.y, x0.z, x0.w, x1.x, x1.y, x1.z, x1.w};
                if (BN_IN) {
                    int kb = quad * 8 + kk * 32;
#pragma unroll
                    for (int j = 0; j < 8; ++j) {
                        float t = av[j] * cA[kb + j] + cB[kb + j];
                        av[j] = fmaxf(t, 0.01f * t);
                    }
                }
                uint4 fu;
                fu.x = packbf2(av[0], av[1]); fu.y = packbf2(av[2], av[3]);
                fu.z = packbf2(av[4], av[5]); fu.w = packbf2(av[6], av[7]);
                afr[kk] = __builtin_bit_cast(bf16x8, fu);
            }
        }

        f32x4 acc[4] = {{0.f, 0.f, 0.f, 0.f}, {0.f, 0.f, 0.f, 0.f},
                        {0.f, 0.f, 0.f, 0.f}, {0.f, 0.f, 0.f, 0.f}};
#pragma unroll
        for (int t = 0; t < 4; ++t) {
            acc[t] = __builtin_amdgcn_mfma_f32_16x16x32_bf16(afr[0], bfr[t][0], acc[t], 0, 0, 0);
            acc[t] = __builtin_amdgcn_mfma_f32_16x16x32_bf16(afr[1], bfr[t][1], acc[t], 0, 0, 0);
        }

        // epilogue: D row = r0 + w*16 + quad*4 + r, col = c0 + t*16 + n16
#pragma unroll
        for (int t = 0; t < 4; ++t) {
            int col = c0 + t * 16 + n16;
            float bv = bias[col];
#pragma unroll
            for (int r = 0; r < 4; ++r) {
                int row = r0 + w * 16 + quad * 4 + r;
                if (row < GN) {
                    float o = acc[t][r] + bv;
                    if (RESID) o += resid[(size_t)row * dst_ld + col];
                    if (F32OUT) dst[(size_t)row * dst_ld + col] = o;
                    if (BF16OUT) dstb[(size_t)row * dstb_ld + col] = bf16rn(o);
                    if (STATS) { ls[t] += o; lq[t] += o * o; }
                }
            }
        }
    }

    if (STATS) {
        if (tid < 64) { sS[tid] = 0.f; sQ[tid] = 0.f; }
        __syncthreads();
#pragma unroll
        for (int t = 0; t < 4; ++t) {
            float s = ls[t], q = lq[t];
            s += __shfl_down(s, 16, 64); s += __shfl_down(s, 32, 64);
            q += __shfl_down(q, 16, 64); q += __shfl_down(q, 32, 64);
            if (lane < 16) {
                atomicAdd(&sS[t * 16 + n16], s);
                atomicAdd(&sQ[t * 16 + n16], q);
            }
        }
        __syncthreads();
        if (tid < 64) {
            atomicAdd(&statsOutSum[c0 + tid], sS[tid]);
            atomicAdd(&statsOutSq[c0 + tid], sQ[tid]);
        }
    }
}

// ---------------- classifier tail (bf16 y1) ----------------

__global__ __launch_bounds__(256) void cls2_kernel(
    const unsigned short* __restrict__ y1b,
    const float* __restrict__ sum, const float* __restrict__ sq,
    const float* __restrict__ bnw, const float* __restrict__ bnb,
    const float* __restrict__ w2, const float* __restrict__ b2,
    float* __restrict__ out) {
    int node = blockIdx.x * 4 + (threadIdx.x >> 6);
    int d = threadIdx.x & 63;
    if (node >= GN) return;
    float partial = 0.f;
#pragma unroll
    for (int hh = 0; hh < 2; ++hh) {
        int c = d + hh * 64;
        float m = sum[c] / FN;
        float var = sq[c] / FN - m * m;
        float a = rsqrtf(var + BN_EPS) * bnw[c];
        float v = bfu16(y1b[(size_t)node * 128 + c]);
        v = v * a + (bnb[c] - m * a);
        v = fmaxf(v, 0.01f * v);
        partial += v * w2[c];
    }
    for (int o = 32; o >= 1; o >>= 1) partial += __shfl_down(partial, o, 64);
    if (d == 0) out[node] = partial + b2[0];
}

// ---------------- launcher ----------------

extern "C" void kernel_launch(void* const* d_in, const int* in_sizes, int n_in,
                              void* d_out, int out_size, void* d_ws, size_t ws_size,
                              hipStream_t stream) {
    (void)in_sizes; (void)n_in; (void)out_size; (void)ws_size;
    const float* x    = (const float*)d_in[0];
    const int*   ei   = (const int*)d_in[1];
    const float* attr = (const float*)d_in[2];
    const float* bnpw = (const float*)d_in[3];
    const float* bnpb = (const float*)d_in[4];
    const float* elw  = (const float*)d_in[5];
    const float* elb  = (const float*)d_in[6];
    const float* l1w  = (const float*)d_in[7];
    const float* l1b  = (const float*)d_in[8];
    const float* bnmw = (const float*)d_in[9];
    const float* bnmb = (const float*)d_in[10];
    const float* l2w  = (const float*)d_in[11];
    const float* l2b  = (const float*)d_in[12];
    const float* epsA = (const float*)d_in[13];
    const float* c1w  = (const float*)d_in[14];
    const float* c1b  = (const float*)d_in[15];
    const float* cbw  = (const float*)d_in[16];
    const float* cbb  = (const float*)d_in[17];
    const float* c2w  = (const float*)d_in[18];
    const float* c2b  = (const float*)d_in[19];
    const int* srcArr = ei;
    const int* dstArr = ei + GE;

    char* base = (char*)d_ws;
    size_t ofs = 0;
    auto alloc = [&](size_t bytes) {
        void* p = base + ofs;
        ofs = (ofs + bytes + 1023) & ~(size_t)1023;
        return p;
    };
    int* off              = (int*)alloc((size_t)(GN + 1) * 4);
    int* hist1            = (int*)alloc((size_t)256 * SB * 4);
    int* hist2            = (int*)alloc((size_t)512 * SB * 4);
    int* binTot1          = (int*)alloc(512 * 4);
    int* binTot2          = (int*)alloc(512 * 4);
    int* src_sorted       = (int*)alloc((size_t)GE * 4);
    unsigned* attr_sorted = (unsigned*)alloc((size_t)GE * 32);  // packed rows, 32B
    unsigned short* wbf   = (unsigned short*)alloc(40960 * 2);
    float* stP0 = (float*)alloc(512);
    float* stP1 = (float*)alloc(512);
    float* stM  = (float*)alloc(512);
    float* stC  = (float*)alloc(1024);
    float* h = (float*)alloc((size_t)GN * 256);
    float* z = (float*)alloc((size_t)GN * 256);
    unsigned short* zb = (unsigned short*)alloc((size_t)GN * 128);
    unsigned short* xb = (unsigned short*)alloc((size_t)GN * 128);
    unsigned short* hb = (unsigned short*)alloc((size_t)GN * 128);
    unsigned short* y1b = (unsigned short*)attr_sorted;  // reuse (25.6MB <= 51.2MB)
    // Radix ping-pong pairs alias z (25.6MB = 2 x GE*8B); z is first written
    // by layer-0 gemm1, long after the sort chain is done (stream-ordered).
    uint2* pairsA = (uint2*)z;
    uint2* pairsB = (uint2*)((char*)z + (size_t)GE * 8);

    float* stP[2] = {stP0, stP1};

    // ---- deterministic 2-pass radix sort by dst (no global atomics) ----
    h1_kernel<<<SB, 256, 0, stream>>>(dstArr, hist1, l1w, l2w, c1w, wbf, stP0);
    s1_kernel<<<256, 256, 0, stream>>>(hist1, binTot1);
    s2_kernel<<<1, 256, 0, stream>>>(binTot1, 256);
    scat1_kernel<<<SB, 256, 0, stream>>>(dstArr, hist1, binTot1, pairsA);
    h2_kernel<<<SB, 256, 0, stream>>>(pairsA, hist2);
    s1_kernel<<<512, 256, 0, stream>>>(hist2, binTot2);
    s2_kernel<<<1, 256, 0, stream>>>(binTot2, 512);
    scat2_kernel<<<SB, 256, 0, stream>>>(pairsA, hist2, binTot2, pairsB);
    off_kernel<<<392, 256, 0, stream>>>(pairsB, off);
    gather_sorted_kernel<<<4096, 256, 0, stream>>>(pairsB, srcArr, (const float4*)attr,
                                                   src_sorted, (uint2*)attr_sorted);

    // ---- layer-0 pre-BN stats on x (+ x -> bf16) ----
    col_stats64<<<512, 256, 0, stream>>>(x, stP0, stP0 + 64, xb);

    const unsigned short* hbsrc = xb;
    for (int i = 0; i < 4; ++i) {
        float* sIn = stP[i & 1];
        float* sNext = stP[(i + 1) & 1];
        if (i == 0)
            aggregate_kernel<0><<<25000, 256, 0, stream>>>(
                hbsrc, sIn, sIn + 64, bnpw + i * 64, bnpb + i * 64,
                off, src_sorted, attr_sorted, elw + i * 1024, elb + i * 64, epsA, i,
                zb, stM);
        else
            aggregate_kernel<1><<<25000, 256, 0, stream>>>(
                hbsrc, sIn, sIn + 64, bnpw + i * 64, bnpb + i * 64,
                off, src_sorted, attr_sorted, elw + i * 1024, elb + i * 64, epsA, i,
                zb, stM);
        // gemm1: z = zb @ l1w^T + b ; stats -> stM ; zero next stats buffer
        gemm_mfma<false, true, true, false, false, true><<<dim3(782, 1), 256, 0, stream>>>(
            nullptr, zb, 64, wbf + i * 4096, l1b + i * 64, z, 64, nullptr, 0, nullptr,
            nullptr, nullptr, nullptr, nullptr, stM, stM + 64,
            (i == 3) ? stC : sNext, (i == 3) ? 256 : 128);
        // gemm2: h = leaky(bn(z)) @ l2w^T + b [+h] ; stats -> sNext ; bf16 copy
        if (i == 0)
            gemm_mfma<true, false, true, false, true, true><<<dim3(782, 1), 256, 0, stream>>>(
                z, nullptr, 64, wbf + 16384 + i * 4096, l2b + i * 64, h, 64, hb, 64,
                nullptr, stM, stM + 64, bnmw + i * 64, bnmb + i * 64,
                sNext, sNext + 64, nullptr, 0);
        else if (i < 3)
            gemm_mfma<true, false, true, true, true, true><<<dim3(782, 1), 256, 0, stream>>>(
                z, nullptr, 64, wbf + 16384 + i * 4096, l2b + i * 64, h, 64, hb, 64,
                h, stM, stM + 64, bnmw + i * 64, bnmb + i * 64,
                sNext, sNext + 64, nullptr, 0);
        else
            gemm_mfma<true, false, false, true, true, true><<<dim3(782, 1), 256, 0, stream>>>(
                z, nullptr, 64, wbf + 16384 + i * 4096, l2b + i * 64, h, 64, hb, 64,
                h, stM, stM + 64, bnmw + i * 64, bnmb + i * 64,
                nullptr, nullptr, nullptr, 0);
        hbsrc = hb;
    }

    // ---- classifier: y1b = hb @ c1w^T + b (bf16 out only), then BN+leaky+dot ----
    dim3 gc(391, 2);
    gemm_mfma<false, true, true, false, true, false><<<gc, 256, 0, stream>>>(
        nullptr, hb, 64, wbf + 32768, c1b, nullptr, 128, y1b, 128, nullptr,
        nullptr, nullptr, nullptr, nullptr, stC, stC + 128, nullptr, 0);
    cls2_kernel<<<25000, 256, 0, stream>>>(y1b, stC, stC + 128, cbw, cbb, c2w, c2b,
                                           (float*)d_out);
}